// Round 25
// baseline (530.177 us; speedup 1.0000x reference)
//
#include <hip/hip_runtime.h>

#define N96 884736
#define N48 110592
#define N24 13824
#define N12 1728
#define N6  216

typedef __attribute__((ext_vector_type(4))) short short4v;
typedef __attribute__((ext_vector_type(8))) short short8v;
typedef __attribute__((ext_vector_type(4))) float f32x4;

static __device__ __forceinline__ float lrelu_f(float x){ return x >= 0.f ? x : 0.2f*x; }
static __device__ __forceinline__ int clampi(int v,int lo,int hi){ return v<lo?lo:(v>hi?hi:v); }

// fp32 -> bf16 (RNE) raw bits in short
static __device__ __forceinline__ short f2bf(float x){
    unsigned u = __builtin_bit_cast(unsigned, x);
    unsigned r = (u + 0x7FFFu + ((u >> 16) & 1u)) >> 16;
    return (short)r;
}

// ---------------- shared conv body: 3^3 conv, stride S, SAME (fp32 direct) ----------------
template<int OCPB, int S, bool RELU>
static __device__ __forceinline__ void conv_body(
    const float* __restrict__ in1, int C1,
    const float* __restrict__ in2, int C2,
    const float* __restrict__ w, const float* __restrict__ b,
    float* __restrict__ out, int ID, int OD,
    long out_cstride, int out_vmul, int t, int oc0)
{
    int i2 = t % OD; int r = t / OD; int i1 = r % OD; int i0 = r / OD;

    float acc[OCPB];
    #pragma unroll
    for (int j=0; j<OCPB; ++j) acc[j] = b[oc0+j];

    int zz[3], yy[3], xx[3]; bool zv[3], yv[3], xv[3];
    #pragma unroll
    for (int k=0; k<3; ++k){
        int a0 = (S==2) ? (2*i0+k) : (i0+k-1);
        int a1 = (S==2) ? (2*i1+k) : (i1+k-1);
        int a2 = (S==2) ? (2*i2+k) : (i2+k-1);
        zz[k]=a0; zv[k]=(a0>=0)&&(a0<ID);
        yy[k]=a1; yv[k]=(a1>=0)&&(a1<ID);
        xx[k]=a2; xv[k]=(a2>=0)&&(a2<ID);
    }
    const int C = C1 + C2;
    const int ID2 = ID*ID;
    const long ID3 = (long)ID2*ID;

    for (int s=0; s<2; ++s){
        const float* ip = s ? in2 : in1;
        int Cs  = s ? C2 : C1;
        int icb = s ? C1 : 0;
        if (Cs == 0) continue;
        for (int ic=0; ic<Cs; ++ic){
            const float* ipb = ip + (long)ic*ID3;
            float v[27];
            #pragma unroll
            for (int kd=0; kd<3; ++kd)
            #pragma unroll
            for (int kh=0; kh<3; ++kh)
            #pragma unroll
            for (int kw=0; kw<3; ++kw){
                bool ok = zv[kd] && yv[kh] && xv[kw];
                v[kd*9+kh*3+kw] = ok ? ipb[(long)zz[kd]*ID2 + yy[kh]*ID + xx[kw]] : 0.f;
            }
            const float* wbase = w + ((long)oc0*C + (icb+ic))*27;
            #pragma unroll
            for (int j=0; j<OCPB; ++j){
                const float* wo = wbase + (long)j*C*27;
                float sacc = 0.f;
                #pragma unroll
                for (int k=0; k<27; ++k) sacc += wo[k]*v[k];
                acc[j] += sacc;
            }
        }
    }
    #pragma unroll
    for (int j=0; j<OCPB; ++j){
        float o = RELU ? lrelu_f(acc[j]) : acc[j];
        out[(long)(oc0+j)*out_cstride + (long)t*out_vmul] = o;
    }
}

template<int OCPB, int S, bool RELU>
__global__ void conv3d_k(const float* __restrict__ in1, int C1,
                         const float* __restrict__ in2, int C2,
                         const float* __restrict__ w, const float* __restrict__ b,
                         float* __restrict__ out, int ID, int OD,
                         long out_cstride, int out_vmul)
{
    int nvox = OD*OD*OD;
    int t = blockIdx.x*blockDim.x + threadIdx.x;
    if (t >= nvox) return;
    conv_body<OCPB,S,RELU>(in1,C1,in2,C2,w,b,out,ID,OD,out_cstride,out_vmul,t,blockIdx.y*OCPB);
}

// dual-path conv: blockIdx.z selects {A,B} parameter set (cnn path / enc path fused)
template<int OCPB, int S, bool RELU>
__global__ void conv3d_dual_k(const float* __restrict__ in1A, const float* __restrict__ in2A,
                              const float* __restrict__ in1B, const float* __restrict__ in2B,
                              int C1, int C2,
                              const float* __restrict__ wA, const float* __restrict__ bA,
                              const float* __restrict__ wB, const float* __restrict__ bB,
                              float* __restrict__ outA, float* __restrict__ outB,
                              int ID, int OD)
{
    int nvox = OD*OD*OD;
    int t = blockIdx.x*blockDim.x + threadIdx.x;
    if (t >= nvox) return;
    long nv = nvox;
    if (blockIdx.z == 0)
        conv_body<OCPB,S,RELU>(in1A,C1,in2A,C2,wA,bA,outA,ID,OD,nv,1,t,blockIdx.y*OCPB);
    else
        conv_body<OCPB,S,RELU>(in1B,C1,in2B,C2,wB,bB,outB,ID,OD,nv,1,t,blockIdx.y*OCPB);
}

// ---------------- E0 (16ch fp32 ch-major @48^3) -> CLE0 [48^3][16] bf16 ----------------
__global__ void e0cl16_k(const float* __restrict__ e0, short* __restrict__ cl){
    int t = blockIdx.x*blockDim.x + threadIdx.x;
    if (t >= N48) return;
    short8v v0, v1;
    #pragma unroll
    for (int c=0;c<8;++c){ v0[c] = f2bf(e0[(long)c*N48 + t]); v1[c] = f2bf(e0[(long)(8+c)*N48 + t]); }
    *(short8v*)(cl + (long)t*16)     = v0;
    *(short8v*)(cl + (long)t*16 + 8) = v1;
}

// ---------------- stage 2 MFMA (enc): 48^3 CL16 bf16 -> 24^3 stride-2 conv, O=32, fp32 ch-major ----------------
__global__ __launch_bounds__(256, 2)
void conv_s2mfma_k(const short* __restrict__ cl,    // [48^3][16] bf16
                   const short* __restrict__ pack,  // [2][27][64][8] (C=16: g>=2 zero)
                   const float* __restrict__ b,
                   float* __restrict__ out)         // 32ch fp32 ch-major @24^3
{
    const short8v zero8 = {0,0,0,0,0,0,0,0};
    int lane = threadIdx.x & 63;
    int nb = gridDim.x;                              // 432 (divisible by 8)
    int bid = blockIdx.x;
    int sb = (bid & 7)*(nb >> 3) + (bid >> 3);
    int wid = sb*4 + (threadIdx.x >> 6);             // 0..1727
    int ot = wid & 1;
    int s  = wid >> 1;                               // strip 0..863
    int l15 = lane & 15, g = lane >> 4;
    int vL = s*16 + l15;
    int xL = vL % 24; int rL = vL/24; int yL = rL % 24; int zL = rL/24;
    const bool gok = (g < 2);

    float bias = b[ot*16 + l15];
    f32x4 acc = {bias,bias,bias,bias};

    #pragma unroll
    for (int kz=0; kz<3; ++kz){
        int iz = 2*zL + kz; bool okz = (iz < 48);
        int izc = okz ? iz : 0;
        #pragma unroll
        for (int ky=0; ky<3; ++ky){
            int iy = 2*yL + ky; bool oky = (iy < 48);
            int iyc = oky ? iy : 0;
            #pragma unroll
            for (int kx=0; kx<3; ++kx){
                int ix = 2*xL + kx; bool okx = (ix < 48);
                int ixc = okx ? ix : 0;
                bool ok = okz && oky && okx && gok;
                long base = (((long)izc*48 + iyc)*48 + ixc)*16 + (gok ? 8*g : 0);
                short8v a = *(const short8v*)(cl + base);
                if (!ok) a = zero8;
                int kidx = kz*9 + ky*3 + kx;
                short8v wfr = *(const short8v*)(pack + (((long)ot*27 + kidx)*64 + lane)*8);
                acc = __builtin_amdgcn_mfma_f32_16x16x32_bf16(a, wfr, acc, 0, 0, 0);
            }
        }
    }

    int oc = ot*16 + l15;
    #pragma unroll
    for (int reg=0; reg<4; ++reg){
        int m = 4*g + reg;
        out[(long)oc*N24 + s*16 + m] = lrelu_f(acc[reg]);
    }
}

// ---------------- E3 (32ch fp32 ch-major @6^3) -> CLE3 [216][32] bf16 ----------------
__global__ void e3cl_k(const float* __restrict__ e3, short* __restrict__ cl){
    int t = blockIdx.x*blockDim.x + threadIdx.x;
    if (t >= N6) return;
    #pragma unroll
    for (int grp=0; grp<4; ++grp){
        short8v v;
        #pragma unroll
        for (int c=0;c<8;++c) v[c] = f2bf(e3[(long)(8*grp+c)*N6 + t]);
        *(short8v*)(cl + (long)t*32 + 8*grp) = v;
    }
}

// ---------------- fill CL64 ch32..47 from E0 (16ch fp32 ch-major @48^3); zero 48..63 ----------------
__global__ void fill_e0_k(const float* __restrict__ e0, short* __restrict__ cl){
    int t = blockIdx.x*blockDim.x + threadIdx.x;
    if (t >= N48) return;
    short8v v0, v1;
    #pragma unroll
    for (int c=0;c<8;++c)  v0[c] = f2bf(e0[(long)c*N48 + t]);
    #pragma unroll
    for (int c=0;c<8;++c)  v1[c] = f2bf(e0[(long)(8+c)*N48 + t]);
    short8v z = {0,0,0,0,0,0,0,0};
    *(short8v*)(cl + (long)t*64 + 32) = v0;
    *(short8v*)(cl + (long)t*64 + 40) = v1;
    *(short8v*)(cl + (long)t*64 + 48) = z;
    *(short8v*)(cl + (long)t*64 + 56) = z;
}

// ---------------- fill CL64 ch32..63 from a 32ch fp32 ch-major tensor (size NV) ----------------
template<int NV>
__global__ void fill_skip32_k(const float* __restrict__ e, short* __restrict__ cl){
    int t = blockIdx.x*blockDim.x + threadIdx.x;
    if (t >= NV) return;
    #pragma unroll
    for (int grp=0; grp<4; ++grp){
        short8v v;
        #pragma unroll
        for (int c=0;c<8;++c) v[c] = f2bf(e[(long)(8*grp+c)*NV + t]);
        *(short8v*)(cl + (long)t*64 + 32 + 8*grp) = v;
    }
}

// ---------------- combined weight packing (one launch) ----------------
static __device__ __forceinline__ void pack_std_d(const float* __restrict__ w, short* __restrict__ pack,
                                                  int t, int CREAL, int OCREAL){
    int kidx = t >> 6, lane = t & 63;
    int oc = lane & 15, g = lane >> 4;
    short8v f;
    #pragma unroll
    for (int j=0;j<8;++j){
        int ic = 8*g + j;
        float val = (oc < OCREAL && ic < CREAL) ? w[((long)oc*CREAL + ic)*27 + kidx] : 0.f;
        f[j] = f2bf(val);
    }
    *(short8v*)(pack + (long)t*8) = f;
}
static __device__ __forceinline__ void pack_2x2_d(const float* __restrict__ w, short* __restrict__ pack,
                                                  int t, int C){
    int lane = t & 63;
    int r = t >> 6;
    int kidx = r % 27;
    int kt = (r/27) & 1;
    int ot = r/54;
    int oc = ot*16 + (lane & 15), g = lane >> 4;
    short8v f;
    #pragma unroll
    for (int j=0;j<8;++j){
        int ic = kt*32 + 8*g + j;
        float val = (ic < C) ? w[((long)oc*C + ic)*27 + kidx] : 0.f;
        f[j] = f2bf(val);
    }
    *(short8v*)(pack + (long)t*8) = f;
}
static __device__ __forceinline__ void pack_up_d(const float* __restrict__ w, short* __restrict__ pack, int t){
    int lane = t & 63;
    int r = t >> 6;
    int kidx = r % 27;
    int ot = r/27;
    int oc = ot*16 + (lane & 15), g = lane >> 4;
    short8v f;
    #pragma unroll
    for (int j=0;j<8;++j){
        int ic = 8*g + j;
        f[j] = f2bf(w[((long)oc*32 + ic)*27 + kidx]);
    }
    *(short8v*)(pack + (long)t*8) = f;
}
// stage-2: O=32, C=16 -> [ot(2)][27][64][8], ic = 8g+j (<16 real)
static __device__ __forceinline__ void pack_s2_d(const float* __restrict__ w, short* __restrict__ pack, int t){
    int lane = t & 63;
    int r = t >> 6;
    int kidx = r % 27;
    int ot = r/27;
    int oc = ot*16 + (lane & 15), g = lane >> 4;
    short8v f;
    #pragma unroll
    for (int j=0;j<8;++j){
        int ic = 8*g + j;
        float val = (ic < 16) ? w[((long)oc*16 + ic)*27 + kidx] : 0.f;
        f[j] = f2bf(val);
    }
    *(short8v*)(pack + (long)t*8) = f;
}

__global__ void pack_all_k(const float* __restrict__ dw3, const float* __restrict__ fw,
                           const float* __restrict__ uw3,
                           const float* __restrict__ dw2, const float* __restrict__ dw1,
                           const float* __restrict__ dw0,
                           const float* __restrict__ uw2, const float* __restrict__ uw1,
                           const float* __restrict__ uw0,
                           const float* __restrict__ ew1,
                           short* __restrict__ PK3, short* __restrict__ PKF, short* __restrict__ PKU,
                           short* __restrict__ PK2, short* __restrict__ PK1, short* __restrict__ PK0,
                           short* __restrict__ PKU2, short* __restrict__ PKU1, short* __restrict__ PKU0,
                           short* __restrict__ PKE1)
{
    int t = blockIdx.x*blockDim.x + threadIdx.x;
    const int S1 = 27*64;        // 1728
    const int S4 = 4*27*64;      // 6912
    const int S2 = 2*27*64;      // 3456
    if (t < S1){ pack_std_d(dw3, PK3, t, 18, 16); return; } t -= S1;
    if (t < S1){ pack_std_d(fw,  PKF, t, 16,  3); return; } t -= S1;
    if (t < S1){ pack_std_d(uw3, PKU, t, 32, 16); return; } t -= S1;
    if (t < S4){ pack_2x2_d(dw2, PK2, t, 48); return; } t -= S4;
    if (t < S4){ pack_2x2_d(dw1, PK1, t, 64); return; } t -= S4;
    if (t < S4){ pack_2x2_d(dw0, PK0, t, 64); return; } t -= S4;
    if (t < S2){ pack_up_d(uw2, PKU2, t); return; } t -= S2;
    if (t < S2){ pack_up_d(uw1, PKU1, t); return; } t -= S2;
    if (t < S2){ pack_up_d(uw0, PKU0, t); return; } t -= S2;
    if (t < S2){ pack_s2_d(ew1, PKE1, t); return; }
}

// ---------------- MFMA implicit-GEMM 3^3 conv, stride 1, 96^3, OC<=16 ----------------
// R18 structure (x-split + 2 z-rows per wave, 3 strips, LDS-staged weights, lb(256,4)).
// CSTR any multiple of 8; k-groups with 8g >= CSTR compile-select zero.
template<int CSTR, int OCREAL, bool RELU, int OMODE>
__global__ __launch_bounds__(256, 4)
void conv_mfma2_k(const short* __restrict__ cl,
                  const short* __restrict__ pack,
                  const float* __restrict__ b,
                  void* __restrict__ outp)
{
    const int D2 = 96*96;
    const short8v zero8 = {0,0,0,0,0,0,0,0};
    __shared__ short lwfr[27*64*8];                 // 27.6 KB
    for (int idx = threadIdx.x; idx < 27*64; idx += 256)
        *(short8v*)(lwfr + (long)idx*8) = *(const short8v*)(pack + (long)idx*8);
    __syncthreads();

    int lane = threadIdx.x & 63;
    int nb = gridDim.x;                             // 2304
    int bid = blockIdx.x;
    int sb = (bid & 7)*(nb >> 3) + (bid >> 3);      // XCD -> contiguous z-slab
    int wid = sb*4 + (threadIdx.x >> 6);            // 0..9215: (z-pair, y, xh)
    int l15 = lane & 15, g = lane >> 4;
    int xh = wid & 1;
    int rem = wid >> 1;                             // 0..4607
    int y = rem % 96;
    int z = (rem / 96)*2;                           // 0,2,...,94
    int x0b = xh*48;
    const bool gok = (8*g < CSTR);
    const int go = gok ? 8*g : 0;

    float bias = (l15 < OCREAL) ? b[l15] : 0.f;
    f32x4 acc[2][3];
    #pragma unroll
    for (int o=0;o<2;++o)
    #pragma unroll
    for (int i=0;i<3;++i) acc[o][i] = (f32x4){bias,bias,bias,bias};

    #pragma unroll
    for (int dzr=-1; dzr<=2; ++dzr){
        int zz = z + dzr;
        bool okz = (zz>=0) && (zz<96);
        int zc = okz ? zz : z;
        #pragma unroll
        for (int dy=-1; dy<=1; ++dy){
            int yy = y+dy;
            bool okrow = okz && (yy>=0) && (yy<96);
            int yc = (yy>=0 && yy<96) ? yy : y;
            long rowb = (long)zc*D2 + (long)yc*96;
            #pragma unroll
            for (int dx=-1; dx<=1; ++dx){
                short8v a[3];
                #pragma unroll
                for (int i=0;i<3;++i){
                    int x = x0b + 16*i + l15 + dx;
                    bool okx = (x>=0) && (x<96);
                    int xc = okx ? x : (x0b + 16*i + l15);
                    a[i] = *(const short8v*)(cl + (rowb + xc)*CSTR + go);
                    bool oka = okrow && okx && gok;
                    if (!oka) a[i] = zero8;
                }
                if (dzr >= -1 && dzr <= 1){
                    int kidx = (dzr+1)*9 + (dy+1)*3 + (dx+1);
                    short8v wfr = *(const short8v*)(lwfr + ((long)kidx*64 + lane)*8);
                    #pragma unroll
                    for (int i=0;i<3;++i)
                        acc[0][i] = __builtin_amdgcn_mfma_f32_16x16x32_bf16(a[i], wfr, acc[0][i], 0, 0, 0);
                }
                if (dzr >= 0 && dzr <= 2){
                    int kidx = (dzr)*9 + (dy+1)*3 + (dx+1);
                    short8v wfr = *(const short8v*)(lwfr + ((long)kidx*64 + lane)*8);
                    #pragma unroll
                    for (int i=0;i<3;++i)
                        acc[1][i] = __builtin_amdgcn_mfma_f32_16x16x32_bf16(a[i], wfr, acc[1][i], 0, 0, 0);
                }
            }
        }
    }

    #pragma unroll
    for (int o=0;o<2;++o){
        long vrow = (long)(z+o)*D2 + (long)y*96 + x0b;
        if (OMODE == 0){
            short* op = (short*)outp;               // CL bf16 [vox][16]
            #pragma unroll
            for (int i=0;i<3;++i)
            #pragma unroll
            for (int reg=0; reg<4; ++reg){
                int mr = 4*g + reg;
                float v = RELU ? lrelu_f(acc[o][i][reg]) : acc[o][i][reg];
                op[(vrow + 16*i + mr)*16 + l15] = f2bf(v);
            }
        } else {
            float* op = (float*)outp;               // vel fp32 [vox][3]
            if (l15 < 3){
                #pragma unroll
                for (int i=0;i<3;++i)
                #pragma unroll
                for (int reg=0; reg<4; ++reg){
                    int mr = 4*g + reg;
                    op[(vrow + 16*i + mr)*3 + l15] = acc[o][i][reg];
                }
            }
        }
    }
}

// ---------------- MFMA conv dec2: 48^3, C=48(pad 64), O=32 ----------------
// R25: block = (4 rows, ONE octile via blockIdx.y); this block's 54 KB pack half staged
// in LDS. Moves the 108-per-wave wfr stream off the L1 port (R23/R24 evidence: time
// invariant to occupancy & per-wave load structure -> L1/TA port is the saturated
// resource; wfr is half the load instructions). Wave: 162 MFMA, 162 A-loads (L1),
// 54 ds_read_b128 (LDS port). Tap order + kt0->kt1 unchanged -> bit-identical.
__global__ __launch_bounds__(256, 2)
void conv_mfma48_k(const short* __restrict__ cl,    // [48^3][64] bf16
                   const short* __restrict__ pack,  // [2][2][27][64][8]
                   const float* __restrict__ b,
                   short* __restrict__ out)         // [48^3][32] bf16
{
    const int D2 = 48*48;
    const short8v zero8 = {0,0,0,0,0,0,0,0};
    __shared__ short lwfr[2*27*64*8];               // 54 KB (this block's ot half)
    int ot = blockIdx.y;
    for (int idx = threadIdx.x; idx < 2*27*64; idx += 256)
        *(short8v*)(lwfr + (long)idx*8) = *(const short8v*)(pack + ((long)ot*2*27*64 + idx)*8);
    __syncthreads();

    int lane = threadIdx.x & 63;
    int nb = gridDim.x;                              // 576
    int bid = blockIdx.x;
    int sb = (bid & 7)*(nb >> 3) + (bid >> 3);       // XCD z-slab swizzle
    int wid = sb*4 + (threadIdx.x >> 6);             // row 0..2303
    int l15 = lane & 15, g = lane >> 4;
    int y = wid % 48, z = wid / 48;

    float bias = b[ot*16 + l15];
    f32x4 acc[3];
    #pragma unroll
    for (int i=0;i<3;++i) acc[i] = (f32x4){bias,bias,bias,bias};

    #pragma unroll
    for (int dz=-1; dz<=1; ++dz){
        int zz = z+dz;
        bool okz = (zz>=0) && (zz<48);
        int zc = okz ? zz : z;
        #pragma unroll
        for (int dy=-1; dy<=1; ++dy){
            int yy = y+dy;
            bool okzy = okz && (yy>=0) && (yy<48);
            int yc = (yy>=0 && yy<48) ? yy : y;
            long rowb = (long)zc*D2 + (long)yc*48;
            #pragma unroll
            for (int dx=-1; dx<=1; ++dx){
                int kidx = (dz+1)*9 + (dy+1)*3 + (dx+1);
                short8v wfr0 = *(const short8v*)(lwfr + (((long)0*27 + kidx)*64 + lane)*8);
                short8v wfr1 = *(const short8v*)(lwfr + (((long)1*27 + kidx)*64 + lane)*8);
                #pragma unroll
                for (int i=0;i<3;++i){
                    int x = 16*i + l15 + dx;
                    bool okx = (x>=0) && (x<48);
                    int xc = okx ? x : (16*i + l15);
                    bool ok = okzy && okx;
                    long base = (rowb + xc)*64 + 8*g;
                    short8v a0 = *(const short8v*)(cl + base);
                    short8v a1 = *(const short8v*)(cl + base + 32);
                    if (!ok){ a0 = zero8; a1 = zero8; }
                    acc[i] = __builtin_amdgcn_mfma_f32_16x16x32_bf16(a0, wfr0, acc[i], 0, 0, 0);
                    acc[i] = __builtin_amdgcn_mfma_f32_16x16x32_bf16(a1, wfr1, acc[i], 0, 0, 0);
                }
            }
        }
    }

    long vrow = (long)z*D2 + (long)y*48;
    #pragma unroll
    for (int i=0;i<3;++i)
    #pragma unroll
    for (int reg=0; reg<4; ++reg){
        int mr = 4*g + reg;
        out[(vrow + 16*i + mr)*32 + ot*16 + l15] = f2bf(lrelu_f(acc[i][reg]));
    }
}

// ---------------- MFMA conv (dim D): D^3, C=64 (real+skip), O=32 -> CL32 bf16 ----------------
template<int D>
__global__ __launch_bounds__(256, 2)
void conv_mfmaD_k(const short* __restrict__ cl,    // [D^3][64] bf16
                  const short* __restrict__ pack,  // [2][2][27][64][8]
                  const float* __restrict__ b,
                  short* __restrict__ out)         // [D^3][32] bf16
{
    const short8v zero8 = {0,0,0,0,0,0,0,0};
    int lane = threadIdx.x & 63;
    int nb = gridDim.x;
    int bid = blockIdx.x;
    int sb = ((nb & 7) == 0) ? ((bid & 7)*(nb >> 3) + (bid >> 3)) : bid;
    int wid = sb*4 + (threadIdx.x >> 6);
    int ot = wid & 1;
    int s  = wid >> 1;                               // strip
    int l15 = lane & 15, g = lane >> 4;
    int vL = s*16 + l15;
    int xL = vL % D; int rL = vL/D; int yL = rL % D; int zL = rL/D;

    float bias = b[ot*16 + l15];
    f32x4 acc = {bias,bias,bias,bias};

    #pragma unroll
    for (int dz=-1; dz<=1; ++dz){
        int iz = zL+dz; bool okz = (iz>=0)&&(iz<D); int izc = okz?iz:zL;
        #pragma unroll
        for (int dy=-1; dy<=1; ++dy){
            int iy = yL+dy; bool oky = (iy>=0)&&(iy<D); int iyc = oky?iy:yL;
            #pragma unroll
            for (int dx=-1; dx<=1; ++dx){
                int ix = xL+dx; bool okx = (ix>=0)&&(ix<D); int ixc = okx?ix:xL;
                bool ok = okz && oky && okx;
                long base = (((long)izc*D + iyc)*D + ixc)*64;
                int kidx = (dz+1)*9 + (dy+1)*3 + (dx+1);
                #pragma unroll
                for (int kt=0; kt<2; ++kt){
                    short8v wfr = *(const short8v*)(pack + (((long)(ot*2+kt)*27 + kidx)*64 + lane)*8);
                    short8v a = *(const short8v*)(cl + base + kt*32 + 8*g);
                    if (!ok) a = zero8;
                    acc = __builtin_amdgcn_mfma_f32_16x16x32_bf16(a, wfr, acc, 0, 0, 0);
                }
            }
        }
    }

    #pragma unroll
    for (int reg=0; reg<4; ++reg){
        int m = 4*g + reg;
        out[(long)(s*16 + m)*32 + ot*16 + l15] = f2bf(lrelu_f(acc[reg]));
    }
}

// ---------------- MFMA transposed conv (up): [IDI^3][32] bf16 -> [OD^3][64] ch0-31 ----------------
template<int IDI, int NST>
__global__ __launch_bounds__(256, 2)
void convt_mfmaup_k(const short* __restrict__ cl,   // [IDI^3][32] bf16
                    const short* __restrict__ pack, // [2][27][64][8]
                    const float* __restrict__ b,
                    short* __restrict__ o)          // [(2*IDI)^3][64] bf16 (ch0-31)
{
    const int D2i = IDI*IDI;
    const int OD = 2*IDI;
    const long D2o = (long)OD*OD;
    int lane = threadIdx.x & 63;
    int nb = gridDim.x;
    int bid = blockIdx.x;
    int sb = ((nb & 7) == 0) ? ((bid & 7)*(nb >> 3) + (bid >> 3)) : bid;
    int wid = sb*4 + (threadIdx.x >> 6);
    int px = wid & 1;
    int row = wid >> 1;                              // 0..OD*OD-1
    int y = row % OD, z = row / OD;
    int l15 = lane & 15, g = lane >> 4;
    int pz = z & 1, py = y & 1, hz = z >> 1, hy = y >> 1;

    float bias0 = b[l15], bias1 = b[16 + l15];
    f32x4 acc[2][NST];
    #pragma unroll
    for (int i=0;i<NST;++i){ acc[0][i] = (f32x4){bias0,bias0,bias0,bias0};
                             acc[1][i] = (f32x4){bias1,bias1,bias1,bias1}; }

    int k0s[2], izs[2], nz=0;
    if (pz){ k0s[0]=1; izs[0]=hz; nz=1; }
    else { if (hz>=1){ k0s[nz]=0; izs[nz]=hz-1; ++nz; } k0s[nz]=2; izs[nz]=hz; ++nz; }
    int k1s[2], iys[2], ny=0;
    if (py){ k1s[0]=1; iys[0]=hy; ny=1; }
    else { if (hy>=1){ k1s[ny]=0; iys[ny]=hy-1; ++ny; } k1s[ny]=2; iys[ny]=hy; ++ny; }

    for (int a=0;a<nz;++a)
    for (int c=0;c<ny;++c){
        long rowb = (long)izs[a]*D2i + (long)iys[c]*IDI;
        int kbase = k0s[a]*9 + k1s[c]*3;
        int nqx = px?1:2;
        for (int qx=0; qx<nqx; ++qx){
            int k2 = px ? 1 : 2*qx;
            int xoff = px ? 0 : (qx-1);
            short8v av[NST];
            #pragma unroll
            for (int i=0;i<NST;++i){
                int ix = 16*i + l15 + xoff;
                av[i] = (short8v){0,0,0,0,0,0,0,0};
                if (ix >= 0 && ix < IDI) av[i] = *(const short8v*)(cl + ((rowb + ix)*32 + 8*g));
            }
            #pragma unroll
            for (int ot=0; ot<2; ++ot){
                short8v wfr = *(const short8v*)(pack + (((long)ot*27 + kbase + k2)*64 + lane)*8);
                #pragma unroll
                for (int i=0;i<NST;++i)
                    acc[ot][i] = __builtin_amdgcn_mfma_f32_16x16x32_bf16(av[i], wfr, acc[ot][i], 0, 0, 0);
            }
        }
    }

    // store: x_out = 2*(16i + 4g + reg) + px, only m < IDI
    #pragma unroll
    for (int ot=0; ot<2; ++ot)
    #pragma unroll
    for (int i=0;i<NST;++i)
    #pragma unroll
    for (int reg=0; reg<4; ++reg){
        int m = 16*i + 4*g + reg;
        if (m < IDI){
            long vox = (long)z*D2o + (long)y*OD + (2*m + px);
            o[vox*64 + ot*16 + l15] = f2bf(lrelu_f(acc[ot][i][reg]));
        }
    }
}

// ---------------- MFMA transposed conv up3: [48^3][32] bf16 -> CL24 [96^3][24] bf16 ----------------
// Output container is 24 slots: acc ch0-15, src ch16, tgt ch17, zeros ch18-23.
__global__ __launch_bounds__(256, 2)
void convt_mfma96_k(const short* __restrict__ cl,   // [48^3][32] bf16
                    const short* __restrict__ pack, // [27][64][8]
                    const float* __restrict__ b,
                    const float* __restrict__ src,
                    const float* __restrict__ tgt,
                    short* __restrict__ o)          // [96^3][24] bf16
{
    const int D2i = 48*48;
    const long D2o = 96*96;
    int lane = threadIdx.x & 63;
    int nb = gridDim.x;                              // 4608
    int bid = blockIdx.x;
    int sb = (bid & 7)*(nb >> 3) + (bid >> 3);       // XCD z-slab swizzle
    int wid = sb*4 + (threadIdx.x >> 6);             // 0..18431
    int px = wid & 1;
    int row = wid >> 1;                              // 0..9215
    int y = row % 96, z = row / 96;
    int l15 = lane & 15, g = lane >> 4;
    int pz = z & 1, py = y & 1, hz = z >> 1, hy = y >> 1;

    float bias = b[l15];
    f32x4 acc[3];
    #pragma unroll
    for (int i=0;i<3;++i) acc[i] = (f32x4){bias,bias,bias,bias};

    int k0s[2], izs[2], nz=0;
    if (pz){ k0s[0]=1; izs[0]=hz; nz=1; }
    else { if (hz>=1){ k0s[nz]=0; izs[nz]=hz-1; ++nz; } k0s[nz]=2; izs[nz]=hz; ++nz; }
    int k1s[2], iys[2], ny=0;
    if (py){ k1s[0]=1; iys[0]=hy; ny=1; }
    else { if (hy>=1){ k1s[ny]=0; iys[ny]=hy-1; ++ny; } k1s[ny]=2; iys[ny]=hy; ++ny; }

    for (int a=0;a<nz;++a)
    for (int c=0;c<ny;++c){
        long rowb = (long)izs[a]*D2i + (long)iys[c]*48;
        int kbase = k0s[a]*9 + k1s[c]*3;
        int nqx = px?1:2;
        for (int qx=0; qx<nqx; ++qx){
            int k2 = px ? 1 : 2*qx;
            int xoff = px ? 0 : (qx-1);
            short8v wfr = *(const short8v*)(pack + ((long)(kbase+k2)*64 + lane)*8);
            #pragma unroll
            for (int i=0;i<3;++i){
                int ix = 16*i + l15 + xoff;          // ix <= 47 always; check lower bound
                short8v av = {0,0,0,0,0,0,0,0};
                if (ix >= 0) av = *(const short8v*)(cl + ((rowb + ix)*32 + 8*g));
                acc[i] = __builtin_amdgcn_mfma_f32_16x16x32_bf16(av, wfr, acc[i], 0, 0, 0);
            }
        }
    }

    // store: x_out = 2*(16i + 4g + reg) + px
    #pragma unroll
    for (int i=0;i<3;++i)
    #pragma unroll
    for (int reg=0; reg<4; ++reg){
        int m = 16*i + 4*g + reg;
        long vox = (long)z*D2o + (long)y*96 + (2*m + px);
        o[vox*24 + l15] = f2bf(lrelu_f(acc[i][reg]));
        if (l15 == 0)      o[vox*24 + 16] = f2bf(src[vox]);
        else if (l15 == 1) o[vox*24 + 17] = f2bf(tgt[vox]);
        else if (l15 < 8)  o[vox*24 + 16 + l15] = 0;   // ch18..23 zero
    }
}

// ---------------- affine head ----------------
static __device__ void mat4mul(const double* A, const double* B, double* C){
    for (int i=0;i<4;++i) for (int j=0;j<4;++j){
        double s=0; for (int k=0;k<4;++k) s += A[i*4+k]*B[k*4+j];
        C[i*4+j]=s;
    }
}

__global__ void affine_k(const float* __restrict__ c4, float* __restrict__ aff_out, float* __restrict__ mats){
    __shared__ float p[7];
    int t = threadIdx.x;
    if (t < 7){
        float s = 0.f;
        for (int i=0;i<N6;++i) s += c4[t*N6 + i];
        p[t] = s / (float)N6;
        aff_out[t] = p[t];
    }
    __syncthreads();
    if (t == 0){
        double M[16];
        for (int i=0;i<16;++i) M[i]=0.0;
        M[0*4+3]=p[0]; M[1*4+3]=p[1]; M[2*4+3]=p[2];
        M[0*4+1]= p[3]; M[1*4+0]=-p[3];
        M[0*4+2]= p[4]; M[2*4+0]=-p[4];
        M[1*4+2]= p[5]; M[2*4+1]=-p[5];
        M[0*4+0]+=p[6]; M[1*4+1]+=p[6]; M[2*4+2]+=p[6];
        double nrm=0.0;
        for (int i=0;i<4;++i){
            double s=0; for (int j=0;j<4;++j) s += fabs(M[i*4+j]);
            if (s>nrm) nrm=s;
        }
        int jj=0;
        while (nrm > 0.25 && jj < 40){ nrm *= 0.5; ++jj; }
        double sc = 1.0; for (int q=0;q<jj;++q) sc *= 0.5;
        double Ms[16]; for (int i=0;i<16;++i) Ms[i]=M[i]*sc;
        double E[16], T[16], Tn[16];
        for (int i=0;i<16;++i){ E[i] = (i%5==0)?1.0:0.0; T[i]=E[i]; }
        for (int k=1;k<=18;++k){
            mat4mul(T, Ms, Tn);
            double inv = 1.0/(double)k;
            for (int i=0;i<16;++i){ T[i]=Tn[i]*inv; E[i]+=T[i]; }
        }
        for (int q=0;q<jj;++q){ mat4mul(E,E,Tn); for (int i=0;i<16;++i) E[i]=Tn[i]; }
        const double tsh = -48.0;
        for (int i=0;i<3;++i){
            for (int j=0;j<3;++j) mats[i*3+j] = (float)E[i*4+j];
            double rs = (E[i*4+0] - (i==0?1.0:0.0))
                      + (E[i*4+1] - (i==1?1.0:0.0))
                      + (E[i*4+2] - (i==2?1.0:0.0));
            mats[9+i] = (float)(E[i*4+3] + rs*tsh);
        }
    }
}

// ---------------- trilinear helpers ----------------
static __device__ __forceinline__ void trilerp3(const float* __restrict__ f, int D,
                                                float c0, float c1, float c2, float out3[3]){
    float f0=floorf(c0), f1=floorf(c1), f2=floorf(c2);
    float w0=c0-f0, w1=c1-f1, w2=c2-f2;
    int a0=(int)f0, a1=(int)f1, a2=(int)f2;
    int i0s[2]={clampi(a0,0,D-1), clampi(a0+1,0,D-1)};
    int i1s[2]={clampi(a1,0,D-1), clampi(a1+1,0,D-1)};
    int i2s[2]={clampi(a2,0,D-1), clampi(a2+1,0,D-1)};
    float w0s[2]={1.f-w0,w0}, w1s[2]={1.f-w1,w1}, w2s[2]={1.f-w2,w2};
    out3[0]=out3[1]=out3[2]=0.f;
    #pragma unroll
    for (int dx=0;dx<2;++dx)
    #pragma unroll
    for (int dy=0;dy<2;++dy)
    #pragma unroll
    for (int dz=0;dz<2;++dz){
        float wg = w0s[dx]*w1s[dy]*w2s[dz];
        const float* pp = f + ((i0s[dx]*D + i1s[dy])*D + i2s[dz])*3;
        out3[0]+=wg*pp[0]; out3[1]+=wg*pp[1]; out3[2]+=wg*pp[2];
    }
}

static __device__ __forceinline__ float trilerp1(const float* __restrict__ f, int D,
                                                 float c0, float c1, float c2){
    float f0=floorf(c0), f1=floorf(c1), f2=floorf(c2);
    float w0=c0-f0, w1=c1-f1, w2=c2-f2;
    int a0=(int)f0, a1=(int)f1, a2=(int)f2;
    int i0s[2]={clampi(a0,0,D-1), clampi(a0+1,0,D-1)};
    int i1s[2]={clampi(a1,0,D-1), clampi(a1+1,0,D-1)};
    int i2s[2]={clampi(a2,0,D-1), clampi(a2+1,0,D-1)};
    float w0s[2]={1.f-w0,w0}, w1s[2]={1.f-w1,w1}, w2s[2]={1.f-w2,w2};
    float s=0.f;
    #pragma unroll
    for (int dx=0;dx<2;++dx)
    #pragma unroll
    for (int dy=0;dy<2;++dy)
    #pragma unroll
    for (int dz=0;dz<2;++dz){
        float wg = w0s[dx]*w1s[dy]*w2s[dz];
        s += wg * f[(i0s[dx]*D + i1s[dy])*D + i2s[dz]];
    }
    return s;
}

// ---------------- vel -> d0 ----------------
__global__ void resize_small_k(const float* __restrict__ vel, float* __restrict__ dA){
    int t = blockIdx.x*blockDim.x + threadIdx.x;
    if (t >= N48) return;
    int i2 = t % 48; int r = t / 48; int i1 = r % 48; int i0 = r / 48;
    const float s = 95.f/47.f;
    float o[3];
    trilerp3(vel, 96, i0*s, i1*s, i2*s, o);
    const float k = 0.5f/256.f;
    dA[t*3+0]=o[0]*k; dA[t*3+1]=o[1]*k; dA[t*3+2]=o[2]*k;
}

// ---------------- squaring iteration ----------------
__global__ void sq_k(const float* __restrict__ din, float* __restrict__ dout){
    int t = blockIdx.x*blockDim.x + threadIdx.x;
    if (t >= N48) return;
    int i2 = t % 48; int r = t / 48; int i1 = r % 48; int i0 = r / 48;
    float d0=din[t*3+0], d1=din[t*3+1], d2=din[t*3+2];
    float s[3];
    trilerp3(din, 48, (float)i0+d0, (float)i1+d1, (float)i2+d2, s);
    dout[t*3+0]=d0+s[0]; dout[t*3+1]=d1+s[1]; dout[t*3+2]=d2+s[2];
}

// ---------------- fused grid upsample + affine + final pull ----------------
__global__ void grid_pull_k(const float* __restrict__ dfin, const float* __restrict__ src,
                            const float* __restrict__ mats, float* __restrict__ out){
    int t = blockIdx.x*blockDim.x + threadIdx.x;
    if (t >= N96) return;
    int i2 = t % 96; int r = t / 96; int i1 = r % 96; int i0 = r / 96;
    const float sc = 47.f/95.f;
    float c0=i0*sc, c1=i1*sc, c2=i2*sc;
    float s[3];
    trilerp3(dfin, 48, c0, c1, c2, s);
    float g0 = 2.f*(c0+s[0]), g1 = 2.f*(c1+s[1]), g2 = 2.f*(c2+s[2]);
    float L00=mats[0],L01=mats[1],L02=mats[2],L10=mats[3],L11=mats[4],L12=mats[5],
          L20=mats[6],L21=mats[7],L22=mats[8],o0=mats[9],o1=mats[10],o2=mats[11];
    float gg0 = L00*g0 + L01*g1 + L02*g2 + o0;
    float gg1 = L10*g0 + L11*g1 + L12*g2 + o1;
    float gg2 = L20*g0 + L21*g1 + L22*g2 + o2;
    bool inb = (gg0>=0.f)&&(gg0<=95.f)&&(gg1>=0.f)&&(gg1<=95.f)&&(gg2>=0.f)&&(gg2<=95.f);
    float val = trilerp1(src, 96, gg0, gg1, gg2);
    out[t] = inb ? val : 0.f;
}

// ---------------- host side ----------------
extern "C" void kernel_launch(void* const* d_in, const int* in_sizes, int n_in,
                              void* d_out, int out_size, void* d_ws, size_t ws_size,
                              hipStream_t stream) {
    const float* src = (const float*)d_in[0];
    const float* tgt = (const float*)d_in[1];
    const float *cw[5], *cb[5], *ew[4], *eb[4], *uw[4], *ub[4], *dw[4], *db[4];
    for (int i=0;i<5;++i){ cw[i]=(const float*)d_in[2+2*i]; cb[i]=(const float*)d_in[3+2*i]; }
    for (int i=0;i<4;++i){ ew[i]=(const float*)d_in[12+2*i]; eb[i]=(const float*)d_in[13+2*i]; }
    for (int i=0;i<4;++i){ uw[i]=(const float*)d_in[20+2*i]; ub[i]=(const float*)d_in[21+2*i]; }
    for (int i=0;i<4;++i){ dw[i]=(const float*)d_in[28+2*i]; db[i]=(const float*)d_in[29+2*i]; }
    const float* fw = (const float*)d_in[36];
    const float* fb = (const float*)d_in[37];

    float* ws = (float*)d_ws;
    const long OFF_E0 = 0;                       // 16 ch @48^3 fp32 (enc stage1)
    const long OFF_CLE0 = OFF_E0 + 16L*N48;      // [48^3][16] bf16 = 8*N48 fl
    const long OFF_E1 = OFF_CLE0 + 8L*N48;       // 32 @24^3 fp32
    const long OFF_E2 = OFF_E1 + 32L*N24;        // 32 @12^3
    const long OFF_E3 = OFF_E2 + 32L*N12;        // 32 @6^3
    const long OFF_B1 = OFF_E3 + 32L*N6;         // scratch fp32 (cnn path)
    const long OFF_B2 = OFF_B1 + 32L*N48;
    const long OFF_CL24 = OFF_B2 + 32L*N48;      // [96^3][24] bf16 = 12*N96 floats
    const long OFF_CL16 = OFF_CL24 + 12L*N96;    // [96^3][16] bf16; CL64 aliases here
    const long OFF_DA = OFF_CL16 + 8L*N96;
    const long OFF_DB = OFF_DA + 3L*N48;
    const long OFF_MT = OFF_DB + 3L*N48;
    const long OFF_PK3 = OFF_MT + 16;            // [27][64][8] bf16 = 6912 fl
    const long OFF_PKF = OFF_PK3 + 6912;
    const long OFF_PK2 = OFF_PKF + 6912;         // [2][2][27][64][8] = 27648 fl
    const long OFF_PKU = OFF_PK2 + 27648;        // up3 pack 6912
    const long OFF_PK1 = OFF_PKU + 6912;         // dec1 pack 27648
    const long OFF_PK0 = OFF_PK1 + 27648;        // dec0 pack 27648
    const long OFF_PKU2 = OFF_PK0 + 27648;       // up2 pack 13824
    const long OFF_PKU1 = OFF_PKU2 + 13824;      // up1 pack 13824
    const long OFF_PKU0 = OFF_PKU1 + 13824;      // up0 pack 13824
    const long OFF_PKE1 = OFF_PKU0 + 13824;      // enc stage2 pack 13824
    const long OFF_CLD2 = OFF_PKE1 + 13824;      // [48^3][32] bf16 = 16*N48 fl
    const long OFF_CL64B = OFF_CLD2 + 16L*N48;   // [24^3][64] bf16 = 32*N24 fl
    const long OFF_CLD1 = OFF_CL64B + 32L*N24;   // [24^3][32] bf16 = 16*N24 fl
    const long OFF_CL64C = OFF_CLD1 + 16L*N24;   // [12^3][64] bf16 = 32*N12 fl
    const long OFF_CLD0 = OFF_CL64C + 32L*N12;   // [12^3][32] bf16 = 16*N12 fl
    const long OFF_CLE3 = OFF_CLD0 + 16L*N12;    // [6^3][32] bf16 = 16*N6 fl
    const long WS_TOT = OFF_CLE3 + 16L*N6;
    if (ws_size < (size_t)WS_TOT*4) return;

    float* E0 = ws + OFF_E0;
    short* CLE0 = (short*)(ws + OFF_CLE0);
    float* E1 = ws + OFF_E1;
    float* E2 = ws + OFF_E2;
    float* E3 = ws + OFF_E3;
    float* B1 = ws + OFF_B1;
    float* B2 = ws + OFF_B2;
    short* CL24 = (short*)(ws + OFF_CL24);
    short* CL16 = (short*)(ws + OFF_CL16);
    short* CL64 = (short*)(ws + OFF_CL16);       // alias: CL64 dead before CL16 written
    float* DA = ws + OFF_DA;
    float* DB = ws + OFF_DB;
    float* MT = ws + OFF_MT;
    short* PK3 = (short*)(ws + OFF_PK3);
    short* PKF = (short*)(ws + OFF_PKF);
    short* PK2 = (short*)(ws + OFF_PK2);
    short* PKU = (short*)(ws + OFF_PKU);
    short* PK1 = (short*)(ws + OFF_PK1);
    short* PK0 = (short*)(ws + OFF_PK0);
    short* PKU2 = (short*)(ws + OFF_PKU2);
    short* PKU1 = (short*)(ws + OFF_PKU1);
    short* PKU0 = (short*)(ws + OFF_PKU0);
    short* PKE1 = (short*)(ws + OFF_PKE1);
    short* CLD2 = (short*)(ws + OFF_CLD2);
    short* CL64B = (short*)(ws + OFF_CL64B);
    short* CLD1 = (short*)(ws + OFF_CLD1);
    short* CL64C = (short*)(ws + OFF_CL64C);
    short* CLD0 = (short*)(ws + OFF_CLD0);
    short* CLE3 = (short*)(ws + OFF_CLE3);

    float* out_def = (float*)d_out;
    float* out_vel = out_def + N96;
    float* out_aff = out_vel + 3L*N96;

    auto gsz = [](int n, int b){ return (n + b - 1)/b; };

    // combined weight packing (one launch)
    pack_all_k<<<gsz(39744,256), 256, 0, stream>>>(dw[3], fw, uw[3], dw[2], dw[1], dw[0],
                                                   uw[2], uw[1], uw[0], ew[1],
                                                   PK3, PKF, PKU, PK2, PK1, PK0,
                                                   PKU2, PKU1, PKU0, PKE1);

    // stage 1 (96^3 -> 48^3, C=2, O=16) dual fp32 (R21-verified): cnn -> B1, enc -> E0
    conv3d_dual_k< 8,2,true><<<dim3(gsz(N48,256), 2,2), 256, 0, stream>>>(src,tgt, src,tgt, 1,1, cw[0],cb[0], ew[0],eb[0], B1,E0, 96,48);

    // E0 -> CL16 bf16 (input for enc MFMA stage-2)
    e0cl16_k<<<gsz(N48,256), 256, 0, stream>>>(E0, CLE0);

    // stage 2: cnn path stays fp32 direct (affine precision); enc path -> MFMA
    conv3d_k< 4,2,true><<<dim3(gsz(N24,256), 8), 256, 0, stream>>>(B1,16, nullptr,0, cw[1],cb[1], B2, 48,24, N24, 1);
    conv_s2mfma_k<<<432, 256, 0, stream>>>(CLE0, PKE1, eb[1], E1);

    // remaining cascade (fp32 direct, small): stage3 (24->12), stage4 (12->6), head conv
    conv3d_dual_k< 2,2,true><<<dim3(gsz(N12, 64),16,2),  64, 0, stream>>>(B2,nullptr, E1,nullptr, 32,0, cw[2],cb[2], ew[2],eb[2], B1,E2, 24,12);
    conv3d_dual_k< 1,2,true><<<dim3(gsz(N6 , 64),32,2),  64, 0, stream>>>(B1,nullptr, E2,nullptr, 32,0, cw[3],cb[3], ew[3],eb[3], B2,E3, 12, 6);
    conv3d_k< 1,1,false><<<dim3(gsz(N6 , 64), 7), 64, 0, stream>>>(B2,32, nullptr, 0, cw[4], cb[4], B1, 6, 6, N6, 1);
    affine_k<<<1, 64, 0, stream>>>(B1, out_aff, MT);

    // E3 -> CL bf16 (input for MFMA up0)
    e3cl_k<<<1, 256, 0, stream>>>(E3, CLE3);

    // up0 (MFMA transposed, 6^3 -> 12^3): CLE3 -> CL64C ch0-31; E2 skip -> ch32-63
    convt_mfmaup_k<6,1><<<72, 256, 0, stream>>>(CLE3, PKU0, ub[0], CL64C);
    fill_skip32_k<N12><<<gsz(N12,256), 256, 0, stream>>>(E2, CL64C);

    // dec0 (MFMA): CL64C (C=64) -> CLD0 [12^3][32] bf16
    conv_mfmaD_k<12><<<54, 256, 0, stream>>>(CL64C, PK0, db[0], CLD0);

    // up1 (MFMA transposed): CLD0 -> CL64B ch0-31; E1 skip -> ch32-63
    convt_mfmaup_k<12,1><<<288, 256, 0, stream>>>(CLD0, PKU1, ub[1], CL64B);
    fill_skip32_k<N24><<<gsz(N24,256), 256, 0, stream>>>(E1, CL64B);

    // dec1 (MFMA): CL64B (C=64) -> CLD1 [24^3][32] bf16
    conv_mfmaD_k<24><<<432, 256, 0, stream>>>(CL64B, PK1, db[1], CLD1);

    // up2 (MFMA transposed): CLD1 -> CL64 ch0-31; E0 skip -> ch32-47; zero 48-63
    convt_mfmaup_k<24,2><<<1152, 256, 0, stream>>>(CLD1, PKU2, ub[2], CL64);
    fill_e0_k<<<gsz(N48,256), 256, 0, stream>>>(E0, CL64);

    // dec2 (MFMA, per-octile blocks + 54 KB LDS weight pack): CL64 -> CLD2 [48^3][32] bf16
    conv_mfma48_k<<<dim3(576,2), 256, 0, stream>>>(CL64, PK2, db[2], CLD2);

    // up3 (MFMA transposed): CLD2 -> CL24 [96^3][24] (acc ch0-15, src/tgt ch16/17, zeros 18-23)
    convt_mfma96_k<<<4608, 256, 0, stream>>>(CLD2, PKU, ub[3], src, tgt, CL24);

    // dec3 (MFMA, x-split + 2 z-rows/wave, LDS wfr): CL24 (C=18 real) -> CL16 bf16, lrelu
    conv_mfma2_k<24,16,true ,0><<<2304, 256, 0, stream>>>(CL24, PK3, db[3], (void*)CL16);
    // fin (MFMA, x-split + 2 z-rows/wave, LDS wfr): CL16 -> vel fp32 channel-last
    conv_mfma2_k<16, 3,false,1><<<2304, 256, 0, stream>>>(CL16, PKF, fb, (void*)out_vel);

    // velocity integration
    resize_small_k<<<gsz(N48,256), 256, 0, stream>>>(out_vel, DA);
    float* da = DA; float* dbuf = DB;
    for (int it=0; it<8; ++it){
        sq_k<<<gsz(N48,256), 256, 0, stream>>>(da, dbuf);
        float* tmp = da; da = dbuf; dbuf = tmp;
    }

    // grid upsample + affine + final warp
    grid_pull_k<<<gsz(N96,256), 256, 0, stream>>>(da, src, MT, out_def);
}

// Round 26
// 465.004 us; speedup vs baseline: 1.1402x; 1.1402x over previous
//
#include <hip/hip_runtime.h>

#define N96 884736
#define N48 110592
#define N24 13824
#define N12 1728
#define N6  216

typedef __attribute__((ext_vector_type(4))) short short4v;
typedef __attribute__((ext_vector_type(8))) short short8v;
typedef __attribute__((ext_vector_type(4))) float f32x4;

static __device__ __forceinline__ float lrelu_f(float x){ return x >= 0.f ? x : 0.2f*x; }
static __device__ __forceinline__ int clampi(int v,int lo,int hi){ return v<lo?lo:(v>hi?hi:v); }

// fp32 -> bf16 (RNE) raw bits in short
static __device__ __forceinline__ short f2bf(float x){
    unsigned u = __builtin_bit_cast(unsigned, x);
    unsigned r = (u + 0x7FFFu + ((u >> 16) & 1u)) >> 16;
    return (short)r;
}

// ---------------- shared conv body: 3^3 conv, stride S, SAME (fp32 direct) ----------------
template<int OCPB, int S, bool RELU>
static __device__ __forceinline__ void conv_body(
    const float* __restrict__ in1, int C1,
    const float* __restrict__ in2, int C2,
    const float* __restrict__ w, const float* __restrict__ b,
    float* __restrict__ out, int ID, int OD,
    long out_cstride, int out_vmul, int t, int oc0)
{
    int i2 = t % OD; int r = t / OD; int i1 = r % OD; int i0 = r / OD;

    float acc[OCPB];
    #pragma unroll
    for (int j=0; j<OCPB; ++j) acc[j] = b[oc0+j];

    int zz[3], yy[3], xx[3]; bool zv[3], yv[3], xv[3];
    #pragma unroll
    for (int k=0; k<3; ++k){
        int a0 = (S==2) ? (2*i0+k) : (i0+k-1);
        int a1 = (S==2) ? (2*i1+k) : (i1+k-1);
        int a2 = (S==2) ? (2*i2+k) : (i2+k-1);
        zz[k]=a0; zv[k]=(a0>=0)&&(a0<ID);
        yy[k]=a1; yv[k]=(a1>=0)&&(a1<ID);
        xx[k]=a2; xv[k]=(a2>=0)&&(a2<ID);
    }
    const int C = C1 + C2;
    const int ID2 = ID*ID;
    const long ID3 = (long)ID2*ID;

    for (int s=0; s<2; ++s){
        const float* ip = s ? in2 : in1;
        int Cs  = s ? C2 : C1;
        int icb = s ? C1 : 0;
        if (Cs == 0) continue;
        for (int ic=0; ic<Cs; ++ic){
            const float* ipb = ip + (long)ic*ID3;
            float v[27];
            #pragma unroll
            for (int kd=0; kd<3; ++kd)
            #pragma unroll
            for (int kh=0; kh<3; ++kh)
            #pragma unroll
            for (int kw=0; kw<3; ++kw){
                bool ok = zv[kd] && yv[kh] && xv[kw];
                v[kd*9+kh*3+kw] = ok ? ipb[(long)zz[kd]*ID2 + yy[kh]*ID + xx[kw]] : 0.f;
            }
            const float* wbase = w + ((long)oc0*C + (icb+ic))*27;
            #pragma unroll
            for (int j=0; j<OCPB; ++j){
                const float* wo = wbase + (long)j*C*27;
                float sacc = 0.f;
                #pragma unroll
                for (int k=0; k<27; ++k) sacc += wo[k]*v[k];
                acc[j] += sacc;
            }
        }
    }
    #pragma unroll
    for (int j=0; j<OCPB; ++j){
        float o = RELU ? lrelu_f(acc[j]) : acc[j];
        out[(long)(oc0+j)*out_cstride + (long)t*out_vmul] = o;
    }
}

template<int OCPB, int S, bool RELU>
__global__ void conv3d_k(const float* __restrict__ in1, int C1,
                         const float* __restrict__ in2, int C2,
                         const float* __restrict__ w, const float* __restrict__ b,
                         float* __restrict__ out, int ID, int OD,
                         long out_cstride, int out_vmul)
{
    int nvox = OD*OD*OD;
    int t = blockIdx.x*blockDim.x + threadIdx.x;
    if (t >= nvox) return;
    conv_body<OCPB,S,RELU>(in1,C1,in2,C2,w,b,out,ID,OD,out_cstride,out_vmul,t,blockIdx.y*OCPB);
}

// dual-path conv: blockIdx.z selects {A,B} parameter set (cnn path / enc path fused)
template<int OCPB, int S, bool RELU>
__global__ void conv3d_dual_k(const float* __restrict__ in1A, const float* __restrict__ in2A,
                              const float* __restrict__ in1B, const float* __restrict__ in2B,
                              int C1, int C2,
                              const float* __restrict__ wA, const float* __restrict__ bA,
                              const float* __restrict__ wB, const float* __restrict__ bB,
                              float* __restrict__ outA, float* __restrict__ outB,
                              int ID, int OD)
{
    int nvox = OD*OD*OD;
    int t = blockIdx.x*blockDim.x + threadIdx.x;
    if (t >= nvox) return;
    long nv = nvox;
    if (blockIdx.z == 0)
        conv_body<OCPB,S,RELU>(in1A,C1,in2A,C2,wA,bA,outA,ID,OD,nv,1,t,blockIdx.y*OCPB);
    else
        conv_body<OCPB,S,RELU>(in1B,C1,in2B,C2,wB,bB,outB,ID,OD,nv,1,t,blockIdx.y*OCPB);
}

// ---------------- E0 (16ch fp32 ch-major @48^3) -> CLE0 [48^3][16] bf16 ----------------
__global__ void e0cl16_k(const float* __restrict__ e0, short* __restrict__ cl){
    int t = blockIdx.x*blockDim.x + threadIdx.x;
    if (t >= N48) return;
    short8v v0, v1;
    #pragma unroll
    for (int c=0;c<8;++c){ v0[c] = f2bf(e0[(long)c*N48 + t]); v1[c] = f2bf(e0[(long)(8+c)*N48 + t]); }
    *(short8v*)(cl + (long)t*16)     = v0;
    *(short8v*)(cl + (long)t*16 + 8) = v1;
}

// ---------------- stage 2 MFMA (enc): 48^3 CL16 bf16 -> 24^3 stride-2 conv, O=32, fp32 ch-major ----------------
__global__ __launch_bounds__(256, 2)
void conv_s2mfma_k(const short* __restrict__ cl,    // [48^3][16] bf16
                   const short* __restrict__ pack,  // [2][27][64][8] (C=16: g>=2 zero)
                   const float* __restrict__ b,
                   float* __restrict__ out)         // 32ch fp32 ch-major @24^3
{
    const short8v zero8 = {0,0,0,0,0,0,0,0};
    int lane = threadIdx.x & 63;
    int nb = gridDim.x;                              // 432 (divisible by 8)
    int bid = blockIdx.x;
    int sb = (bid & 7)*(nb >> 3) + (bid >> 3);
    int wid = sb*4 + (threadIdx.x >> 6);             // 0..1727
    int ot = wid & 1;
    int s  = wid >> 1;                               // strip 0..863
    int l15 = lane & 15, g = lane >> 4;
    int vL = s*16 + l15;
    int xL = vL % 24; int rL = vL/24; int yL = rL % 24; int zL = rL/24;
    const bool gok = (g < 2);

    float bias = b[ot*16 + l15];
    f32x4 acc = {bias,bias,bias,bias};

    #pragma unroll
    for (int kz=0; kz<3; ++kz){
        int iz = 2*zL + kz; bool okz = (iz < 48);
        int izc = okz ? iz : 0;
        #pragma unroll
        for (int ky=0; ky<3; ++ky){
            int iy = 2*yL + ky; bool oky = (iy < 48);
            int iyc = oky ? iy : 0;
            #pragma unroll
            for (int kx=0; kx<3; ++kx){
                int ix = 2*xL + kx; bool okx = (ix < 48);
                int ixc = okx ? ix : 0;
                bool ok = okz && oky && okx && gok;
                long base = (((long)izc*48 + iyc)*48 + ixc)*16 + (gok ? 8*g : 0);
                short8v a = *(const short8v*)(cl + base);
                if (!ok) a = zero8;
                int kidx = kz*9 + ky*3 + kx;
                short8v wfr = *(const short8v*)(pack + (((long)ot*27 + kidx)*64 + lane)*8);
                acc = __builtin_amdgcn_mfma_f32_16x16x32_bf16(a, wfr, acc, 0, 0, 0);
            }
        }
    }

    int oc = ot*16 + l15;
    #pragma unroll
    for (int reg=0; reg<4; ++reg){
        int m = 4*g + reg;
        out[(long)oc*N24 + s*16 + m] = lrelu_f(acc[reg]);
    }
}

// ---------------- E3 (32ch fp32 ch-major @6^3) -> CLE3 [216][32] bf16 ----------------
__global__ void e3cl_k(const float* __restrict__ e3, short* __restrict__ cl){
    int t = blockIdx.x*blockDim.x + threadIdx.x;
    if (t >= N6) return;
    #pragma unroll
    for (int grp=0; grp<4; ++grp){
        short8v v;
        #pragma unroll
        for (int c=0;c<8;++c) v[c] = f2bf(e3[(long)(8*grp+c)*N6 + t]);
        *(short8v*)(cl + (long)t*32 + 8*grp) = v;
    }
}

// ---------------- fill CL48 ch32..47 from E0 (16ch fp32 ch-major @48^3); no zero-stores ----------------
__global__ void fill_e0_k(const float* __restrict__ e0, short* __restrict__ cl){
    int t = blockIdx.x*blockDim.x + threadIdx.x;
    if (t >= N48) return;
    short8v v0, v1;
    #pragma unroll
    for (int c=0;c<8;++c)  v0[c] = f2bf(e0[(long)c*N48 + t]);
    #pragma unroll
    for (int c=0;c<8;++c)  v1[c] = f2bf(e0[(long)(8+c)*N48 + t]);
    *(short8v*)(cl + (long)t*48 + 32) = v0;
    *(short8v*)(cl + (long)t*48 + 40) = v1;
}

// ---------------- fill CL64 ch32..63 from a 32ch fp32 ch-major tensor (size NV) ----------------
template<int NV>
__global__ void fill_skip32_k(const float* __restrict__ e, short* __restrict__ cl){
    int t = blockIdx.x*blockDim.x + threadIdx.x;
    if (t >= NV) return;
    #pragma unroll
    for (int grp=0; grp<4; ++grp){
        short8v v;
        #pragma unroll
        for (int c=0;c<8;++c) v[c] = f2bf(e[(long)(8*grp+c)*NV + t]);
        *(short8v*)(cl + (long)t*64 + 32 + 8*grp) = v;
    }
}

// ---------------- combined weight packing (one launch) ----------------
static __device__ __forceinline__ void pack_std_d(const float* __restrict__ w, short* __restrict__ pack,
                                                  int t, int CREAL, int OCREAL){
    int kidx = t >> 6, lane = t & 63;
    int oc = lane & 15, g = lane >> 4;
    short8v f;
    #pragma unroll
    for (int j=0;j<8;++j){
        int ic = 8*g + j;
        float val = (oc < OCREAL && ic < CREAL) ? w[((long)oc*CREAL + ic)*27 + kidx] : 0.f;
        f[j] = f2bf(val);
    }
    *(short8v*)(pack + (long)t*8) = f;
}
static __device__ __forceinline__ void pack_2x2_d(const float* __restrict__ w, short* __restrict__ pack,
                                                  int t, int C){
    int lane = t & 63;
    int r = t >> 6;
    int kidx = r % 27;
    int kt = (r/27) & 1;
    int ot = r/54;
    int oc = ot*16 + (lane & 15), g = lane >> 4;
    short8v f;
    #pragma unroll
    for (int j=0;j<8;++j){
        int ic = kt*32 + 8*g + j;
        float val = (ic < C) ? w[((long)oc*C + ic)*27 + kidx] : 0.f;
        f[j] = f2bf(val);
    }
    *(short8v*)(pack + (long)t*8) = f;
}
static __device__ __forceinline__ void pack_up_d(const float* __restrict__ w, short* __restrict__ pack, int t){
    int lane = t & 63;
    int r = t >> 6;
    int kidx = r % 27;
    int ot = r/27;
    int oc = ot*16 + (lane & 15), g = lane >> 4;
    short8v f;
    #pragma unroll
    for (int j=0;j<8;++j){
        int ic = 8*g + j;
        f[j] = f2bf(w[((long)oc*32 + ic)*27 + kidx]);
    }
    *(short8v*)(pack + (long)t*8) = f;
}
// stage-2: O=32, C=16 -> [ot(2)][27][64][8], ic = 8g+j (<16 real)
static __device__ __forceinline__ void pack_s2_d(const float* __restrict__ w, short* __restrict__ pack, int t){
    int lane = t & 63;
    int r = t >> 6;
    int kidx = r % 27;
    int ot = r/27;
    int oc = ot*16 + (lane & 15), g = lane >> 4;
    short8v f;
    #pragma unroll
    for (int j=0;j<8;++j){
        int ic = 8*g + j;
        float val = (ic < 16) ? w[((long)oc*16 + ic)*27 + kidx] : 0.f;
        f[j] = f2bf(val);
    }
    *(short8v*)(pack + (long)t*8) = f;
}

__global__ void pack_all_k(const float* __restrict__ dw3, const float* __restrict__ fw,
                           const float* __restrict__ uw3,
                           const float* __restrict__ dw2, const float* __restrict__ dw1,
                           const float* __restrict__ dw0,
                           const float* __restrict__ uw2, const float* __restrict__ uw1,
                           const float* __restrict__ uw0,
                           const float* __restrict__ ew1,
                           short* __restrict__ PK3, short* __restrict__ PKF, short* __restrict__ PKU,
                           short* __restrict__ PK2, short* __restrict__ PK1, short* __restrict__ PK0,
                           short* __restrict__ PKU2, short* __restrict__ PKU1, short* __restrict__ PKU0,
                           short* __restrict__ PKE1)
{
    int t = blockIdx.x*blockDim.x + threadIdx.x;
    const int S1 = 27*64;        // 1728
    const int S4 = 4*27*64;      // 6912
    const int S2 = 2*27*64;      // 3456
    if (t < S1){ pack_std_d(dw3, PK3, t, 18, 16); return; } t -= S1;
    if (t < S1){ pack_std_d(fw,  PKF, t, 16,  3); return; } t -= S1;
    if (t < S1){ pack_std_d(uw3, PKU, t, 32, 16); return; } t -= S1;
    if (t < S4){ pack_2x2_d(dw2, PK2, t, 48); return; } t -= S4;
    if (t < S4){ pack_2x2_d(dw1, PK1, t, 64); return; } t -= S4;
    if (t < S4){ pack_2x2_d(dw0, PK0, t, 64); return; } t -= S4;
    if (t < S2){ pack_up_d(uw2, PKU2, t); return; } t -= S2;
    if (t < S2){ pack_up_d(uw1, PKU1, t); return; } t -= S2;
    if (t < S2){ pack_up_d(uw0, PKU0, t); return; } t -= S2;
    if (t < S2){ pack_s2_d(ew1, PKE1, t); return; }
}

// ---------------- MFMA implicit-GEMM 3^3 conv, stride 1, 96^3, OC<=16 ----------------
// R18 structure (x-split + 2 z-rows per wave, 3 strips, LDS-staged weights, lb(256,4)).
// CSTR any multiple of 8; k-groups with 8g >= CSTR compile-select zero.
template<int CSTR, int OCREAL, bool RELU, int OMODE>
__global__ __launch_bounds__(256, 4)
void conv_mfma2_k(const short* __restrict__ cl,
                  const short* __restrict__ pack,
                  const float* __restrict__ b,
                  void* __restrict__ outp)
{
    const int D2 = 96*96;
    const short8v zero8 = {0,0,0,0,0,0,0,0};
    __shared__ short lwfr[27*64*8];                 // 27.6 KB
    for (int idx = threadIdx.x; idx < 27*64; idx += 256)
        *(short8v*)(lwfr + (long)idx*8) = *(const short8v*)(pack + (long)idx*8);
    __syncthreads();

    int lane = threadIdx.x & 63;
    int nb = gridDim.x;                             // 2304
    int bid = blockIdx.x;
    int sb = (bid & 7)*(nb >> 3) + (bid >> 3);      // XCD -> contiguous z-slab
    int wid = sb*4 + (threadIdx.x >> 6);            // 0..9215: (z-pair, y, xh)
    int l15 = lane & 15, g = lane >> 4;
    int xh = wid & 1;
    int rem = wid >> 1;                             // 0..4607
    int y = rem % 96;
    int z = (rem / 96)*2;                           // 0,2,...,94
    int x0b = xh*48;
    const bool gok = (8*g < CSTR);
    const int go = gok ? 8*g : 0;

    float bias = (l15 < OCREAL) ? b[l15] : 0.f;
    f32x4 acc[2][3];
    #pragma unroll
    for (int o=0;o<2;++o)
    #pragma unroll
    for (int i=0;i<3;++i) acc[o][i] = (f32x4){bias,bias,bias,bias};

    #pragma unroll
    for (int dzr=-1; dzr<=2; ++dzr){
        int zz = z + dzr;
        bool okz = (zz>=0) && (zz<96);
        int zc = okz ? zz : z;
        #pragma unroll
        for (int dy=-1; dy<=1; ++dy){
            int yy = y+dy;
            bool okrow = okz && (yy>=0) && (yy<96);
            int yc = (yy>=0 && yy<96) ? yy : y;
            long rowb = (long)zc*D2 + (long)yc*96;
            #pragma unroll
            for (int dx=-1; dx<=1; ++dx){
                short8v a[3];
                #pragma unroll
                for (int i=0;i<3;++i){
                    int x = x0b + 16*i + l15 + dx;
                    bool okx = (x>=0) && (x<96);
                    int xc = okx ? x : (x0b + 16*i + l15);
                    a[i] = *(const short8v*)(cl + (rowb + xc)*CSTR + go);
                    bool oka = okrow && okx && gok;
                    if (!oka) a[i] = zero8;
                }
                if (dzr >= -1 && dzr <= 1){
                    int kidx = (dzr+1)*9 + (dy+1)*3 + (dx+1);
                    short8v wfr = *(const short8v*)(lwfr + ((long)kidx*64 + lane)*8);
                    #pragma unroll
                    for (int i=0;i<3;++i)
                        acc[0][i] = __builtin_amdgcn_mfma_f32_16x16x32_bf16(a[i], wfr, acc[0][i], 0, 0, 0);
                }
                if (dzr >= 0 && dzr <= 2){
                    int kidx = (dzr)*9 + (dy+1)*3 + (dx+1);
                    short8v wfr = *(const short8v*)(lwfr + ((long)kidx*64 + lane)*8);
                    #pragma unroll
                    for (int i=0;i<3;++i)
                        acc[1][i] = __builtin_amdgcn_mfma_f32_16x16x32_bf16(a[i], wfr, acc[1][i], 0, 0, 0);
                }
            }
        }
    }

    #pragma unroll
    for (int o=0;o<2;++o){
        long vrow = (long)(z+o)*D2 + (long)y*96 + x0b;
        if (OMODE == 0){
            short* op = (short*)outp;               // CL bf16 [vox][16]
            #pragma unroll
            for (int i=0;i<3;++i)
            #pragma unroll
            for (int reg=0; reg<4; ++reg){
                int mr = 4*g + reg;
                float v = RELU ? lrelu_f(acc[o][i][reg]) : acc[o][i][reg];
                op[(vrow + 16*i + mr)*16 + l15] = f2bf(v);
            }
        } else {
            float* op = (float*)outp;               // vel fp32 [vox][3]
            if (l15 < 3){
                #pragma unroll
                for (int i=0;i<3;++i)
                #pragma unroll
                for (int reg=0; reg<4; ++reg){
                    int mr = 4*g + reg;
                    op[(vrow + 16*i + mr)*3 + l15] = acc[o][i][reg];
                }
            }
        }
    }
}

// ---------------- MFMA conv dec2: 48^3, C=48 (CL48, no dead channels), O=32, both octiles ----------------
// R26: R23 structure (best measured: 576 blocks, both octiles/wave) with CL48 input:
// a0 = ch0-31 (all g), a1 = ch32-47 (g<2; g>=2 compile-guarded zero, matching PK2's
// zero pack for ic>=48). A-bytes/voxel 128->96 (-25%). Bit-identical accumulation.
__global__ __launch_bounds__(256, 2)
void conv_mfma48_k(const short* __restrict__ cl,    // [48^3][48] bf16
                   const short* __restrict__ pack,  // [2][2][27][64][8]
                   const float* __restrict__ b,
                   short* __restrict__ out)         // [48^3][32] bf16
{
    const int D2 = 48*48;
    const short8v zero8 = {0,0,0,0,0,0,0,0};
    int lane = threadIdx.x & 63;
    int nb = gridDim.x;                              // 576
    int bid = blockIdx.x;
    int sb = (bid & 7)*(nb >> 3) + (bid >> 3);       // XCD z-slab swizzle
    int wid = sb*4 + (threadIdx.x >> 6);             // row 0..2303
    int l15 = lane & 15, g = lane >> 4;
    int y = wid % 48, z = wid / 48;
    const bool g1ok = (g < 2);                       // kt=1 real channels (32-47)
    const int go1 = g1ok ? (32 + 8*g) : 0;           // clamped (avoid OOB)

    float bias0 = b[l15];
    float bias1 = b[16 + l15];
    f32x4 acc[2][3];
    #pragma unroll
    for (int i=0;i<3;++i){ acc[0][i] = (f32x4){bias0,bias0,bias0,bias0};
                           acc[1][i] = (f32x4){bias1,bias1,bias1,bias1}; }

    #pragma unroll
    for (int dz=-1; dz<=1; ++dz){
        int zz = z+dz;
        bool okz = (zz>=0) && (zz<48);
        int zc = okz ? zz : z;
        #pragma unroll
        for (int dy=-1; dy<=1; ++dy){
            int yy = y+dy;
            bool okzy = okz && (yy>=0) && (yy<48);
            int yc = (yy>=0 && yy<48) ? yy : y;
            long rowb = (long)zc*D2 + (long)yc*48;
            #pragma unroll
            for (int dx=-1; dx<=1; ++dx){
                int kidx = (dz+1)*9 + (dy+1)*3 + (dx+1);
                short8v a0[3], a1[3];
                #pragma unroll
                for (int i=0;i<3;++i){
                    int x = 16*i + l15 + dx;
                    bool okx = (x>=0) && (x<48);
                    int xc = okx ? x : (16*i + l15);
                    bool ok = okzy && okx;
                    long base = (rowb + xc)*48;
                    a0[i] = *(const short8v*)(cl + base + 8*g);
                    a1[i] = *(const short8v*)(cl + base + go1);
                    if (!ok) a0[i] = zero8;
                    if (!(ok && g1ok)) a1[i] = zero8;
                }
                #pragma unroll
                for (int ot=0; ot<2; ++ot){
                    short8v wfr0 = *(const short8v*)(pack + (((long)(ot*2+0)*27 + kidx)*64 + lane)*8);
                    short8v wfr1 = *(const short8v*)(pack + (((long)(ot*2+1)*27 + kidx)*64 + lane)*8);
                    #pragma unroll
                    for (int i=0;i<3;++i){
                        acc[ot][i] = __builtin_amdgcn_mfma_f32_16x16x32_bf16(a0[i], wfr0, acc[ot][i], 0, 0, 0);
                        acc[ot][i] = __builtin_amdgcn_mfma_f32_16x16x32_bf16(a1[i], wfr1, acc[ot][i], 0, 0, 0);
                    }
                }
            }
        }
    }

    long vrow = (long)z*D2 + (long)y*48;
    #pragma unroll
    for (int ot=0; ot<2; ++ot)
    #pragma unroll
    for (int i=0;i<3;++i)
    #pragma unroll
    for (int reg=0; reg<4; ++reg){
        int mr = 4*g + reg;
        out[(vrow + 16*i + mr)*32 + ot*16 + l15] = f2bf(lrelu_f(acc[ot][i][reg]));
    }
}

// ---------------- MFMA conv (dim D): D^3, C=64 (real+skip), O=32 -> CL32 bf16 ----------------
template<int D>
__global__ __launch_bounds__(256, 2)
void conv_mfmaD_k(const short* __restrict__ cl,    // [D^3][64] bf16
                  const short* __restrict__ pack,  // [2][2][27][64][8]
                  const float* __restrict__ b,
                  short* __restrict__ out)         // [D^3][32] bf16
{
    const short8v zero8 = {0,0,0,0,0,0,0,0};
    int lane = threadIdx.x & 63;
    int nb = gridDim.x;
    int bid = blockIdx.x;
    int sb = ((nb & 7) == 0) ? ((bid & 7)*(nb >> 3) + (bid >> 3)) : bid;
    int wid = sb*4 + (threadIdx.x >> 6);
    int ot = wid & 1;
    int s  = wid >> 1;                               // strip
    int l15 = lane & 15, g = lane >> 4;
    int vL = s*16 + l15;
    int xL = vL % D; int rL = vL/D; int yL = rL % D; int zL = rL/D;

    float bias = b[ot*16 + l15];
    f32x4 acc = {bias,bias,bias,bias};

    #pragma unroll
    for (int dz=-1; dz<=1; ++dz){
        int iz = zL+dz; bool okz = (iz>=0)&&(iz<D); int izc = okz?iz:zL;
        #pragma unroll
        for (int dy=-1; dy<=1; ++dy){
            int iy = yL+dy; bool oky = (iy>=0)&&(iy<D); int iyc = oky?iy:yL;
            #pragma unroll
            for (int dx=-1; dx<=1; ++dx){
                int ix = xL+dx; bool okx = (ix>=0)&&(ix<D); int ixc = okx?ix:xL;
                bool ok = okz && oky && okx;
                long base = (((long)izc*D + iyc)*D + ixc)*64;
                int kidx = (dz+1)*9 + (dy+1)*3 + (dx+1);
                #pragma unroll
                for (int kt=0; kt<2; ++kt){
                    short8v wfr = *(const short8v*)(pack + (((long)(ot*2+kt)*27 + kidx)*64 + lane)*8);
                    short8v a = *(const short8v*)(cl + base + kt*32 + 8*g);
                    if (!ok) a = zero8;
                    acc = __builtin_amdgcn_mfma_f32_16x16x32_bf16(a, wfr, acc, 0, 0, 0);
                }
            }
        }
    }

    #pragma unroll
    for (int reg=0; reg<4; ++reg){
        int m = 4*g + reg;
        out[(long)(s*16 + m)*32 + ot*16 + l15] = f2bf(lrelu_f(acc[reg]));
    }
}

// ---------------- MFMA transposed conv (up): [IDI^3][32] bf16 -> [OD^3][OSTR] ch0-31 ----------------
template<int IDI, int NST, int OSTR>
__global__ __launch_bounds__(256, 2)
void convt_mfmaup_k(const short* __restrict__ cl,   // [IDI^3][32] bf16
                    const short* __restrict__ pack, // [2][27][64][8]
                    const float* __restrict__ b,
                    short* __restrict__ o)          // [(2*IDI)^3][OSTR] bf16 (ch0-31)
{
    const int D2i = IDI*IDI;
    const int OD = 2*IDI;
    const long D2o = (long)OD*OD;
    int lane = threadIdx.x & 63;
    int nb = gridDim.x;
    int bid = blockIdx.x;
    int sb = ((nb & 7) == 0) ? ((bid & 7)*(nb >> 3) + (bid >> 3)) : bid;
    int wid = sb*4 + (threadIdx.x >> 6);
    int px = wid & 1;
    int row = wid >> 1;                              // 0..OD*OD-1
    int y = row % OD, z = row / OD;
    int l15 = lane & 15, g = lane >> 4;
    int pz = z & 1, py = y & 1, hz = z >> 1, hy = y >> 1;

    float bias0 = b[l15], bias1 = b[16 + l15];
    f32x4 acc[2][NST];
    #pragma unroll
    for (int i=0;i<NST;++i){ acc[0][i] = (f32x4){bias0,bias0,bias0,bias0};
                             acc[1][i] = (f32x4){bias1,bias1,bias1,bias1}; }

    int k0s[2], izs[2], nz=0;
    if (pz){ k0s[0]=1; izs[0]=hz; nz=1; }
    else { if (hz>=1){ k0s[nz]=0; izs[nz]=hz-1; ++nz; } k0s[nz]=2; izs[nz]=hz; ++nz; }
    int k1s[2], iys[2], ny=0;
    if (py){ k1s[0]=1; iys[0]=hy; ny=1; }
    else { if (hy>=1){ k1s[ny]=0; iys[ny]=hy-1; ++ny; } k1s[ny]=2; iys[ny]=hy; ++ny; }

    for (int a=0;a<nz;++a)
    for (int c=0;c<ny;++c){
        long rowb = (long)izs[a]*D2i + (long)iys[c]*IDI;
        int kbase = k0s[a]*9 + k1s[c]*3;
        int nqx = px?1:2;
        for (int qx=0; qx<nqx; ++qx){
            int k2 = px ? 1 : 2*qx;
            int xoff = px ? 0 : (qx-1);
            short8v av[NST];
            #pragma unroll
            for (int i=0;i<NST;++i){
                int ix = 16*i + l15 + xoff;
                av[i] = (short8v){0,0,0,0,0,0,0,0};
                if (ix >= 0 && ix < IDI) av[i] = *(const short8v*)(cl + ((rowb + ix)*32 + 8*g));
            }
            #pragma unroll
            for (int ot=0; ot<2; ++ot){
                short8v wfr = *(const short8v*)(pack + (((long)ot*27 + kbase + k2)*64 + lane)*8);
                #pragma unroll
                for (int i=0;i<NST;++i)
                    acc[ot][i] = __builtin_amdgcn_mfma_f32_16x16x32_bf16(av[i], wfr, acc[ot][i], 0, 0, 0);
            }
        }
    }

    // store: x_out = 2*(16i + 4g + reg) + px, only m < IDI
    #pragma unroll
    for (int ot=0; ot<2; ++ot)
    #pragma unroll
    for (int i=0;i<NST;++i)
    #pragma unroll
    for (int reg=0; reg<4; ++reg){
        int m = 16*i + 4*g + reg;
        if (m < IDI){
            long vox = (long)z*D2o + (long)y*OD + (2*m + px);
            o[vox*OSTR + ot*16 + l15] = f2bf(lrelu_f(acc[ot][i][reg]));
        }
    }
}

// ---------------- MFMA transposed conv up3: [48^3][32] bf16 -> CL24 [96^3][24] bf16 ----------------
// Output container is 24 slots: acc ch0-15, src ch16, tgt ch17, zeros ch18-23.
__global__ __launch_bounds__(256, 2)
void convt_mfma96_k(const short* __restrict__ cl,   // [48^3][32] bf16
                    const short* __restrict__ pack, // [27][64][8]
                    const float* __restrict__ b,
                    const float* __restrict__ src,
                    const float* __restrict__ tgt,
                    short* __restrict__ o)          // [96^3][24] bf16
{
    const int D2i = 48*48;
    const long D2o = 96*96;
    int lane = threadIdx.x & 63;
    int nb = gridDim.x;                              // 4608
    int bid = blockIdx.x;
    int sb = (bid & 7)*(nb >> 3) + (bid >> 3);       // XCD z-slab swizzle
    int wid = sb*4 + (threadIdx.x >> 6);             // 0..18431
    int px = wid & 1;
    int row = wid >> 1;                              // 0..9215
    int y = row % 96, z = row / 96;
    int l15 = lane & 15, g = lane >> 4;
    int pz = z & 1, py = y & 1, hz = z >> 1, hy = y >> 1;

    float bias = b[l15];
    f32x4 acc[3];
    #pragma unroll
    for (int i=0;i<3;++i) acc[i] = (f32x4){bias,bias,bias,bias};

    int k0s[2], izs[2], nz=0;
    if (pz){ k0s[0]=1; izs[0]=hz; nz=1; }
    else { if (hz>=1){ k0s[nz]=0; izs[nz]=hz-1; ++nz; } k0s[nz]=2; izs[nz]=hz; ++nz; }
    int k1s[2], iys[2], ny=0;
    if (py){ k1s[0]=1; iys[0]=hy; ny=1; }
    else { if (hy>=1){ k1s[ny]=0; iys[ny]=hy-1; ++ny; } k1s[ny]=2; iys[ny]=hy; ++ny; }

    for (int a=0;a<nz;++a)
    for (int c=0;c<ny;++c){
        long rowb = (long)izs[a]*D2i + (long)iys[c]*48;
        int kbase = k0s[a]*9 + k1s[c]*3;
        int nqx = px?1:2;
        for (int qx=0; qx<nqx; ++qx){
            int k2 = px ? 1 : 2*qx;
            int xoff = px ? 0 : (qx-1);
            short8v wfr = *(const short8v*)(pack + ((long)(kbase+k2)*64 + lane)*8);
            #pragma unroll
            for (int i=0;i<3;++i){
                int ix = 16*i + l15 + xoff;          // ix <= 47 always; check lower bound
                short8v av = {0,0,0,0,0,0,0,0};
                if (ix >= 0) av = *(const short8v*)(cl + ((rowb + ix)*32 + 8*g));
                acc[i] = __builtin_amdgcn_mfma_f32_16x16x32_bf16(av, wfr, acc[i], 0, 0, 0);
            }
        }
    }

    // store: x_out = 2*(16i + 4g + reg) + px
    #pragma unroll
    for (int i=0;i<3;++i)
    #pragma unroll
    for (int reg=0; reg<4; ++reg){
        int m = 16*i + 4*g + reg;
        long vox = (long)z*D2o + (long)y*96 + (2*m + px);
        o[vox*24 + l15] = f2bf(lrelu_f(acc[i][reg]));
        if (l15 == 0)      o[vox*24 + 16] = f2bf(src[vox]);
        else if (l15 == 1) o[vox*24 + 17] = f2bf(tgt[vox]);
        else if (l15 < 8)  o[vox*24 + 16 + l15] = 0;   // ch18..23 zero
    }
}

// ---------------- affine head ----------------
static __device__ void mat4mul(const double* A, const double* B, double* C){
    for (int i=0;i<4;++i) for (int j=0;j<4;++j){
        double s=0; for (int k=0;k<4;++k) s += A[i*4+k]*B[k*4+j];
        C[i*4+j]=s;
    }
}

__global__ void affine_k(const float* __restrict__ c4, float* __restrict__ aff_out, float* __restrict__ mats){
    __shared__ float p[7];
    int t = threadIdx.x;
    if (t < 7){
        float s = 0.f;
        for (int i=0;i<N6;++i) s += c4[t*N6 + i];
        p[t] = s / (float)N6;
        aff_out[t] = p[t];
    }
    __syncthreads();
    if (t == 0){
        double M[16];
        for (int i=0;i<16;++i) M[i]=0.0;
        M[0*4+3]=p[0]; M[1*4+3]=p[1]; M[2*4+3]=p[2];
        M[0*4+1]= p[3]; M[1*4+0]=-p[3];
        M[0*4+2]= p[4]; M[2*4+0]=-p[4];
        M[1*4+2]= p[5]; M[2*4+1]=-p[5];
        M[0*4+0]+=p[6]; M[1*4+1]+=p[6]; M[2*4+2]+=p[6];
        double nrm=0.0;
        for (int i=0;i<4;++i){
            double s=0; for (int j=0;j<4;++j) s += fabs(M[i*4+j]);
            if (s>nrm) nrm=s;
        }
        int jj=0;
        while (nrm > 0.25 && jj < 40){ nrm *= 0.5; ++jj; }
        double sc = 1.0; for (int q=0;q<jj;++q) sc *= 0.5;
        double Ms[16]; for (int i=0;i<16;++i) Ms[i]=M[i]*sc;
        double E[16], T[16], Tn[16];
        for (int i=0;i<16;++i){ E[i] = (i%5==0)?1.0:0.0; T[i]=E[i]; }
        for (int k=1;k<=18;++k){
            mat4mul(T, Ms, Tn);
            double inv = 1.0/(double)k;
            for (int i=0;i<16;++i){ T[i]=Tn[i]*inv; E[i]+=T[i]; }
        }
        for (int q=0;q<jj;++q){ mat4mul(E,E,Tn); for (int i=0;i<16;++i) E[i]=Tn[i]; }
        const double tsh = -48.0;
        for (int i=0;i<3;++i){
            for (int j=0;j<3;++j) mats[i*3+j] = (float)E[i*4+j];
            double rs = (E[i*4+0] - (i==0?1.0:0.0))
                      + (E[i*4+1] - (i==1?1.0:0.0))
                      + (E[i*4+2] - (i==2?1.0:0.0));
            mats[9+i] = (float)(E[i*4+3] + rs*tsh);
        }
    }
}

// ---------------- trilinear helpers ----------------
static __device__ __forceinline__ void trilerp3(const float* __restrict__ f, int D,
                                                float c0, float c1, float c2, float out3[3]){
    float f0=floorf(c0), f1=floorf(c1), f2=floorf(c2);
    float w0=c0-f0, w1=c1-f1, w2=c2-f2;
    int a0=(int)f0, a1=(int)f1, a2=(int)f2;
    int i0s[2]={clampi(a0,0,D-1), clampi(a0+1,0,D-1)};
    int i1s[2]={clampi(a1,0,D-1), clampi(a1+1,0,D-1)};
    int i2s[2]={clampi(a2,0,D-1), clampi(a2+1,0,D-1)};
    float w0s[2]={1.f-w0,w0}, w1s[2]={1.f-w1,w1}, w2s[2]={1.f-w2,w2};
    out3[0]=out3[1]=out3[2]=0.f;
    #pragma unroll
    for (int dx=0;dx<2;++dx)
    #pragma unroll
    for (int dy=0;dy<2;++dy)
    #pragma unroll
    for (int dz=0;dz<2;++dz){
        float wg = w0s[dx]*w1s[dy]*w2s[dz];
        const float* pp = f + ((i0s[dx]*D + i1s[dy])*D + i2s[dz])*3;
        out3[0]+=wg*pp[0]; out3[1]+=wg*pp[1]; out3[2]+=wg*pp[2];
    }
}

static __device__ __forceinline__ float trilerp1(const float* __restrict__ f, int D,
                                                 float c0, float c1, float c2){
    float f0=floorf(c0), f1=floorf(c1), f2=floorf(c2);
    float w0=c0-f0, w1=c1-f1, w2=c2-f2;
    int a0=(int)f0, a1=(int)f1, a2=(int)f2;
    int i0s[2]={clampi(a0,0,D-1), clampi(a0+1,0,D-1)};
    int i1s[2]={clampi(a1,0,D-1), clampi(a1+1,0,D-1)};
    int i2s[2]={clampi(a2,0,D-1), clampi(a2+1,0,D-1)};
    float w0s[2]={1.f-w0,w0}, w1s[2]={1.f-w1,w1}, w2s[2]={1.f-w2,w2};
    float s=0.f;
    #pragma unroll
    for (int dx=0;dx<2;++dx)
    #pragma unroll
    for (int dy=0;dy<2;++dy)
    #pragma unroll
    for (int dz=0;dz<2;++dz){
        float wg = w0s[dx]*w1s[dy]*w2s[dz];
        s += wg * f[(i0s[dx]*D + i1s[dy])*D + i2s[dz]];
    }
    return s;
}

// ---------------- vel -> d0 ----------------
__global__ void resize_small_k(const float* __restrict__ vel, float* __restrict__ dA){
    int t = blockIdx.x*blockDim.x + threadIdx.x;
    if (t >= N48) return;
    int i2 = t % 48; int r = t / 48; int i1 = r % 48; int i0 = r / 48;
    const float s = 95.f/47.f;
    float o[3];
    trilerp3(vel, 96, i0*s, i1*s, i2*s, o);
    const float k = 0.5f/256.f;
    dA[t*3+0]=o[0]*k; dA[t*3+1]=o[1]*k; dA[t*3+2]=o[2]*k;
}

// ---------------- squaring iteration ----------------
__global__ void sq_k(const float* __restrict__ din, float* __restrict__ dout){
    int t = blockIdx.x*blockDim.x + threadIdx.x;
    if (t >= N48) return;
    int i2 = t % 48; int r = t / 48; int i1 = r % 48; int i0 = r / 48;
    float d0=din[t*3+0], d1=din[t*3+1], d2=din[t*3+2];
    float s[3];
    trilerp3(din, 48, (float)i0+d0, (float)i1+d1, (float)i2+d2, s);
    dout[t*3+0]=d0+s[0]; dout[t*3+1]=d1+s[1]; dout[t*3+2]=d2+s[2];
}

// ---------------- fused grid upsample + affine + final pull ----------------
__global__ void grid_pull_k(const float* __restrict__ dfin, const float* __restrict__ src,
                            const float* __restrict__ mats, float* __restrict__ out){
    int t = blockIdx.x*blockDim.x + threadIdx.x;
    if (t >= N96) return;
    int i2 = t % 96; int r = t / 96; int i1 = r % 96; int i0 = r / 96;
    const float sc = 47.f/95.f;
    float c0=i0*sc, c1=i1*sc, c2=i2*sc;
    float s[3];
    trilerp3(dfin, 48, c0, c1, c2, s);
    float g0 = 2.f*(c0+s[0]), g1 = 2.f*(c1+s[1]), g2 = 2.f*(c2+s[2]);
    float L00=mats[0],L01=mats[1],L02=mats[2],L10=mats[3],L11=mats[4],L12=mats[5],
          L20=mats[6],L21=mats[7],L22=mats[8],o0=mats[9],o1=mats[10],o2=mats[11];
    float gg0 = L00*g0 + L01*g1 + L02*g2 + o0;
    float gg1 = L10*g0 + L11*g1 + L12*g2 + o1;
    float gg2 = L20*g0 + L21*g1 + L22*g2 + o2;
    bool inb = (gg0>=0.f)&&(gg0<=95.f)&&(gg1>=0.f)&&(gg1<=95.f)&&(gg2>=0.f)&&(gg2<=95.f);
    float val = trilerp1(src, 96, gg0, gg1, gg2);
    out[t] = inb ? val : 0.f;
}

// ---------------- host side ----------------
extern "C" void kernel_launch(void* const* d_in, const int* in_sizes, int n_in,
                              void* d_out, int out_size, void* d_ws, size_t ws_size,
                              hipStream_t stream) {
    const float* src = (const float*)d_in[0];
    const float* tgt = (const float*)d_in[1];
    const float *cw[5], *cb[5], *ew[4], *eb[4], *uw[4], *ub[4], *dw[4], *db[4];
    for (int i=0;i<5;++i){ cw[i]=(const float*)d_in[2+2*i]; cb[i]=(const float*)d_in[3+2*i]; }
    for (int i=0;i<4;++i){ ew[i]=(const float*)d_in[12+2*i]; eb[i]=(const float*)d_in[13+2*i]; }
    for (int i=0;i<4;++i){ uw[i]=(const float*)d_in[20+2*i]; ub[i]=(const float*)d_in[21+2*i]; }
    for (int i=0;i<4;++i){ dw[i]=(const float*)d_in[28+2*i]; db[i]=(const float*)d_in[29+2*i]; }
    const float* fw = (const float*)d_in[36];
    const float* fb = (const float*)d_in[37];

    float* ws = (float*)d_ws;
    const long OFF_E0 = 0;                       // 16 ch @48^3 fp32 (enc stage1)
    const long OFF_CLE0 = OFF_E0 + 16L*N48;      // [48^3][16] bf16 = 8*N48 fl
    const long OFF_E1 = OFF_CLE0 + 8L*N48;       // 32 @24^3 fp32
    const long OFF_E2 = OFF_E1 + 32L*N24;        // 32 @12^3
    const long OFF_E3 = OFF_E2 + 32L*N12;        // 32 @6^3
    const long OFF_B1 = OFF_E3 + 32L*N6;         // scratch fp32 (cnn path)
    const long OFF_B2 = OFF_B1 + 32L*N48;
    const long OFF_CL24 = OFF_B2 + 32L*N48;      // [96^3][24] bf16 = 12*N96 floats
    const long OFF_CL16 = OFF_CL24 + 12L*N96;    // [96^3][16] bf16; CL48 aliases here
    const long OFF_DA = OFF_CL16 + 8L*N96;
    const long OFF_DB = OFF_DA + 3L*N48;
    const long OFF_MT = OFF_DB + 3L*N48;
    const long OFF_PK3 = OFF_MT + 16;            // [27][64][8] bf16 = 6912 fl
    const long OFF_PKF = OFF_PK3 + 6912;
    const long OFF_PK2 = OFF_PKF + 6912;         // [2][2][27][64][8] = 27648 fl
    const long OFF_PKU = OFF_PK2 + 27648;        // up3 pack 6912
    const long OFF_PK1 = OFF_PKU + 6912;         // dec1 pack 27648
    const long OFF_PK0 = OFF_PK1 + 27648;        // dec0 pack 27648
    const long OFF_PKU2 = OFF_PK0 + 27648;       // up2 pack 13824
    const long OFF_PKU1 = OFF_PKU2 + 13824;      // up1 pack 13824
    const long OFF_PKU0 = OFF_PKU1 + 13824;      // up0 pack 13824
    const long OFF_PKE1 = OFF_PKU0 + 13824;      // enc stage2 pack 13824
    const long OFF_CLD2 = OFF_PKE1 + 13824;      // [48^3][32] bf16 = 16*N48 fl
    const long OFF_CL64B = OFF_CLD2 + 16L*N48;   // [24^3][64] bf16 = 32*N24 fl
    const long OFF_CLD1 = OFF_CL64B + 32L*N24;   // [24^3][32] bf16 = 16*N24 fl
    const long OFF_CL64C = OFF_CLD1 + 16L*N24;   // [12^3][64] bf16 = 32*N12 fl
    const long OFF_CLD0 = OFF_CL64C + 32L*N12;   // [12^3][32] bf16 = 16*N12 fl
    const long OFF_CLE3 = OFF_CLD0 + 16L*N12;    // [6^3][32] bf16 = 16*N6 fl
    const long WS_TOT = OFF_CLE3 + 16L*N6;
    if (ws_size < (size_t)WS_TOT*4) return;

    float* E0 = ws + OFF_E0;
    short* CLE0 = (short*)(ws + OFF_CLE0);
    float* E1 = ws + OFF_E1;
    float* E2 = ws + OFF_E2;
    float* E3 = ws + OFF_E3;
    float* B1 = ws + OFF_B1;
    float* B2 = ws + OFF_B2;
    short* CL24 = (short*)(ws + OFF_CL24);
    short* CL16 = (short*)(ws + OFF_CL16);
    short* CL48 = (short*)(ws + OFF_CL16);       // alias: CL48 dead before CL16 written
    float* DA = ws + OFF_DA;
    float* DB = ws + OFF_DB;
    float* MT = ws + OFF_MT;
    short* PK3 = (short*)(ws + OFF_PK3);
    short* PKF = (short*)(ws + OFF_PKF);
    short* PK2 = (short*)(ws + OFF_PK2);
    short* PKU = (short*)(ws + OFF_PKU);
    short* PK1 = (short*)(ws + OFF_PK1);
    short* PK0 = (short*)(ws + OFF_PK0);
    short* PKU2 = (short*)(ws + OFF_PKU2);
    short* PKU1 = (short*)(ws + OFF_PKU1);
    short* PKU0 = (short*)(ws + OFF_PKU0);
    short* PKE1 = (short*)(ws + OFF_PKE1);
    short* CLD2 = (short*)(ws + OFF_CLD2);
    short* CL64B = (short*)(ws + OFF_CL64B);
    short* CLD1 = (short*)(ws + OFF_CLD1);
    short* CL64C = (short*)(ws + OFF_CL64C);
    short* CLD0 = (short*)(ws + OFF_CLD0);
    short* CLE3 = (short*)(ws + OFF_CLE3);

    float* out_def = (float*)d_out;
    float* out_vel = out_def + N96;
    float* out_aff = out_vel + 3L*N96;

    auto gsz = [](int n, int b){ return (n + b - 1)/b; };

    // combined weight packing (one launch)
    pack_all_k<<<gsz(39744,256), 256, 0, stream>>>(dw[3], fw, uw[3], dw[2], dw[1], dw[0],
                                                   uw[2], uw[1], uw[0], ew[1],
                                                   PK3, PKF, PKU, PK2, PK1, PK0,
                                                   PKU2, PKU1, PKU0, PKE1);

    // stage 1 (96^3 -> 48^3, C=2, O=16) dual fp32 (R21-verified): cnn -> B1, enc -> E0
    conv3d_dual_k< 8,2,true><<<dim3(gsz(N48,256), 2,2), 256, 0, stream>>>(src,tgt, src,tgt, 1,1, cw[0],cb[0], ew[0],eb[0], B1,E0, 96,48);

    // E0 -> CL16 bf16 (input for enc MFMA stage-2)
    e0cl16_k<<<gsz(N48,256), 256, 0, stream>>>(E0, CLE0);

    // stage 2: cnn path stays fp32 direct (affine precision); enc path -> MFMA
    conv3d_k< 4,2,true><<<dim3(gsz(N24,256), 8), 256, 0, stream>>>(B1,16, nullptr,0, cw[1],cb[1], B2, 48,24, N24, 1);
    conv_s2mfma_k<<<432, 256, 0, stream>>>(CLE0, PKE1, eb[1], E1);

    // remaining cascade (fp32 direct, small): stage3 (24->12), stage4 (12->6), head conv
    conv3d_dual_k< 2,2,true><<<dim3(gsz(N12, 64),16,2),  64, 0, stream>>>(B2,nullptr, E1,nullptr, 32,0, cw[2],cb[2], ew[2],eb[2], B1,E2, 24,12);
    conv3d_dual_k< 1,2,true><<<dim3(gsz(N6 , 64),32,2),  64, 0, stream>>>(B1,nullptr, E2,nullptr, 32,0, cw[3],cb[3], ew[3],eb[3], B2,E3, 12, 6);
    conv3d_k< 1,1,false><<<dim3(gsz(N6 , 64), 7), 64, 0, stream>>>(B2,32, nullptr, 0, cw[4], cb[4], B1, 6, 6, N6, 1);
    affine_k<<<1, 64, 0, stream>>>(B1, out_aff, MT);

    // E3 -> CL bf16 (input for MFMA up0)
    e3cl_k<<<1, 256, 0, stream>>>(E3, CLE3);

    // up0 (MFMA transposed, 6^3 -> 12^3): CLE3 -> CL64C ch0-31; E2 skip -> ch32-63
    convt_mfmaup_k<6,1,64><<<72, 256, 0, stream>>>(CLE3, PKU0, ub[0], CL64C);
    fill_skip32_k<N12><<<gsz(N12,256), 256, 0, stream>>>(E2, CL64C);

    // dec0 (MFMA): CL64C (C=64) -> CLD0 [12^3][32] bf16
    conv_mfmaD_k<12><<<54, 256, 0, stream>>>(CL64C, PK0, db[0], CLD0);

    // up1 (MFMA transposed): CLD0 -> CL64B ch0-31; E1 skip -> ch32-63
    convt_mfmaup_k<12,1,64><<<288, 256, 0, stream>>>(CLD0, PKU1, ub[1], CL64B);
    fill_skip32_k<N24><<<gsz(N24,256), 256, 0, stream>>>(E1, CL64B);

    // dec1 (MFMA): CL64B (C=64) -> CLD1 [24^3][32] bf16
    conv_mfmaD_k<24><<<432, 256, 0, stream>>>(CL64B, PK1, db[1], CLD1);

    // up2 (MFMA transposed): CLD1 -> CL48 ch0-31; E0 skip -> ch32-47 (no dead channels)
    convt_mfmaup_k<24,2,48><<<1152, 256, 0, stream>>>(CLD1, PKU2, ub[2], CL48);
    fill_e0_k<<<gsz(N48,256), 256, 0, stream>>>(E0, CL48);

    // dec2 (MFMA, R23 structure + CL48): CL48 (C=48, no padding) -> CLD2 [48^3][32] bf16
    conv_mfma48_k<<<576, 256, 0, stream>>>(CL48, PK2, db[2], CLD2);

    // up3 (MFMA transposed): CLD2 -> CL24 [96^3][24] (acc ch0-15, src/tgt ch16/17, zeros 18-23)
    convt_mfma96_k<<<4608, 256, 0, stream>>>(CLD2, PKU, ub[3], src, tgt, CL24);

    // dec3 (MFMA, x-split + 2 z-rows/wave, LDS wfr): CL24 (C=18 real) -> CL16 bf16, lrelu
    conv_mfma2_k<24,16,true ,0><<<2304, 256, 0, stream>>>(CL24, PK3, db[3], (void*)CL16);
    // fin (MFMA, x-split + 2 z-rows/wave, LDS wfr): CL16 -> vel fp32 channel-last
    conv_mfma2_k<16, 3,false,1><<<2304, 256, 0, stream>>>(CL16, PKF, fb, (void*)out_vel);

    // velocity integration
    resize_small_k<<<gsz(N48,256), 256, 0, stream>>>(out_vel, DA);
    float* da = DA; float* dbuf = DB;
    for (int it=0; it<8; ++it){
        sq_k<<<gsz(N48,256), 256, 0, stream>>>(da, dbuf);
        float* tmp = da; da = dbuf; dbuf = tmp;
    }

    // grid upsample + affine + final warp
    grid_pull_k<<<gsz(N96,256), 256, 0, stream>>>(da, src, MT, out_def);
}